// Round 2
// baseline (5620.842 us; speedup 1.0000x reference)
//
#include <hip/hip_runtime.h>

#define DIN 128

// ---- degree counting: out_deg[src[e]]++, in_deg[dst[e]]++ ----
__global__ void deg_kernel(const int* __restrict__ src, const int* __restrict__ dst,
                           int* __restrict__ outdeg, int* __restrict__ indeg, int E) {
    int i = blockIdx.x * blockDim.x + threadIdx.x;
    if (i >= E) return;
    atomicAdd(&outdeg[src[i]], 1);
    atomicAdd(&indeg[dst[i]], 1);
}

// ---- norms: 1/sqrt(max(deg,1)) ----
__global__ void norm_kernel(const int* __restrict__ outdeg, const int* __restrict__ indeg,
                            float* __restrict__ ns, float* __restrict__ nd, int n) {
    int i = blockIdx.x * blockDim.x + threadIdx.x;
    if (i >= n) return;
    ns[i] = 1.0f / sqrtf(fmaxf((float)outdeg[i], 1.0f));
    nd[i] = 1.0f / sqrtf(fmaxf((float)indeg[i], 1.0f));
}

// ---- scatter SpMM: agg[dst[e]][:] += x[src[e]][:] * ns[src[e]] ----
// 32 threads per edge, 4 f32 per thread (one float4 = 16B load), 4 atomics.
__global__ void scatter_kernel(const float* __restrict__ x, const float* __restrict__ ns,
                               const int* __restrict__ src, const int* __restrict__ dst,
                               float* __restrict__ agg, int E) {
    int idx = blockIdx.x * blockDim.x + threadIdx.x;
    int e = idx >> 5;
    if (e >= E) return;
    int f0 = (idx & 31) << 2;
    int s = src[e], d = dst[e];
    float sc = ns[s];
    float4 v = *reinterpret_cast<const float4*>(x + (size_t)s * DIN + f0);
    float* ap = agg + (size_t)d * DIN + f0;
    atomicAdd(ap + 0, v.x * sc);
    atomicAdd(ap + 1, v.y * sc);
    atomicAdd(ap + 2, v.z * sc);
    atomicAdd(ap + 3, v.w * sc);
}

// ---- dense GEMM: out[row][c] = act( (A[row] . W[:,c]) * nd[row] + b[c] ) -> f32 ----
// Block = 256 threads handles 64 rows; 4 threads/row (g = tid&3), CPT = DOUT/4 cols each.
// W staged in LDS f32, K-tiled (KT=64), 4 per-group regions with region byte stride
// % 128 == 32 so the 4 column-group b128 broadcasts hit disjoint bank quads.
template <int DOUT, bool RELU>
__global__ __launch_bounds__(256) void gemm_kernel(
    const float* __restrict__ A, const float* __restrict__ W, const float* __restrict__ bias,
    const float* __restrict__ nd, float* __restrict__ out, int n) {
    constexpr int CPT = DOUT / 4;        // cols per thread (32 or 16)
    constexpr int KT = 64;               // k-tile
    constexpr int RS = KT * CPT + 8;     // f32 units per region; byte stride % 128 == 32
    __shared__ __align__(16) float Wl[4 * RS];
    __shared__ float bl[DOUT];

    if (threadIdx.x < DOUT) bl[threadIdx.x] = bias[threadIdx.x];

    int row = blockIdx.x * 64 + (threadIdx.x >> 2);
    int rc = min(row, n - 1);            // clamp so all threads reach barriers
    int g = threadIdx.x & 3;
    const float* a = A + (size_t)rc * DIN;
    const float* wg = Wl + g * RS;

    float acc[CPT];
#pragma unroll
    for (int c = 0; c < CPT; ++c) acc[c] = 0.f;

    for (int k0 = 0; k0 < DIN; k0 += KT) {
        __syncthreads();                 // previous tile fully consumed
        for (int i = threadIdx.x; i < KT * DOUT; i += 256) {
            int kk = i / DOUT, c = i % DOUT;
            Wl[(c / CPT) * RS + kk * CPT + (c % CPT)] = W[(size_t)(k0 + kk) * DOUT + c];
        }
        __syncthreads();

#pragma unroll 4
        for (int kk = 0; kk < KT; kk += 4) {
            float4 av = *reinterpret_cast<const float4*>(a + k0 + kk);
#pragma unroll
            for (int t = 0; t < 4; ++t) {
                float aval = (&av.x)[t];
                const float4* wp = reinterpret_cast<const float4*>(wg + (kk + t) * CPT);
#pragma unroll
                for (int q = 0; q < CPT / 4; ++q) {
                    float4 wv = wp[q];
                    acc[q * 4 + 0] = fmaf(aval, wv.x, acc[q * 4 + 0]);
                    acc[q * 4 + 1] = fmaf(aval, wv.y, acc[q * 4 + 1]);
                    acc[q * 4 + 2] = fmaf(aval, wv.z, acc[q * 4 + 2]);
                    acc[q * 4 + 3] = fmaf(aval, wv.w, acc[q * 4 + 3]);
                }
            }
        }
    }

    if (row < n) {
        float sc = nd[row];
        float* op = out + (size_t)row * DOUT + g * CPT;
#pragma unroll
        for (int c = 0; c < CPT; ++c) {
            float v = fmaf(acc[c], sc, bl[g * CPT + c]);
            if (RELU) v = fmaxf(v, 0.f);
            op[c] = v;
        }
    }
}

extern "C" void kernel_launch(void* const* d_in, const int* in_sizes, int n_in,
                              void* d_out, int out_size, void* d_ws, size_t ws_size,
                              hipStream_t stream) {
    const float* feature = (const float*)d_in[0];
    const int*   src     = (const int*)d_in[1];
    const int*   dst     = (const int*)d_in[2];
    const float* W1      = (const float*)d_in[3];
    const float* b1      = (const float*)d_in[4];
    const float* W2      = (const float*)d_in[5];
    const float* b2      = (const float*)d_in[6];

    const int N = in_sizes[0] / DIN;
    const int E = in_sizes[1];

    char* ws = (char*)d_ws;
    size_t off = 0;
    auto take = [&](size_t bytes) -> void* {
        void* p = ws + off;
        off += (bytes + 255) & ~(size_t)255;
        return p;
    };
    int*   outdeg = (int*)take((size_t)N * 4);
    int*   indeg  = (int*)take((size_t)N * 4);
    float* ns     = (float*)take((size_t)N * 4);
    float* nd     = (float*)take((size_t)N * 4);
    float* agg    = (float*)take((size_t)N * DIN * 4);
    float* h2     = (float*)take((size_t)N * DIN * 4);

    hipMemsetAsync(outdeg, 0, (size_t)N * 4, stream);
    hipMemsetAsync(indeg,  0, (size_t)N * 4, stream);
    hipMemsetAsync(agg,    0, (size_t)N * DIN * 4, stream);

    deg_kernel<<<(E + 255) / 256, 256, 0, stream>>>(src, dst, outdeg, indeg, E);
    norm_kernel<<<(N + 255) / 256, 256, 0, stream>>>(outdeg, indeg, ns, nd, N);

    // Layer 1: scatter (x * ns) into agg, then h2 = relu((agg @ W1) * nd + b1)
    int scatter_blocks = (int)(((size_t)E * 32 + 255) / 256);
    scatter_kernel<<<scatter_blocks, 256, 0, stream>>>(feature, ns, src, dst, agg, E);
    gemm_kernel<128, true><<<(N + 63) / 64, 256, 0, stream>>>(agg, W1, b1, nd, h2, N);

    // Layer 2: re-zero agg, scatter (h2 * ns), then out = (agg @ W2) * nd + b2
    hipMemsetAsync(agg, 0, (size_t)N * DIN * 4, stream);
    scatter_kernel<<<scatter_blocks, 256, 0, stream>>>(h2, ns, src, dst, agg, E);
    gemm_kernel<64, false><<<(N + 63) / 64, 256, 0, stream>>>(agg, W2, b2, nd, (float*)d_out, N);
}

// Round 3
// 694.755 us; speedup vs baseline: 8.0904x; 8.0904x over previous
//
#include <hip/hip_runtime.h>

#define DIN 128

// ---- degree counting ----
__global__ void deg_kernel(const int* __restrict__ src, const int* __restrict__ dst,
                           int* __restrict__ outdeg, int* __restrict__ indeg, int E) {
    int i = blockIdx.x * blockDim.x + threadIdx.x;
    if (i >= E) return;
    atomicAdd(&outdeg[src[i]], 1);
    atomicAdd(&indeg[dst[i]], 1);
}

// ---- norms: 1/sqrt(max(deg,1)) ----
__global__ void norm_kernel(const int* __restrict__ outdeg, const int* __restrict__ indeg,
                            float* __restrict__ ns, float* __restrict__ nd, int n) {
    int i = blockIdx.x * blockDim.x + threadIdx.x;
    if (i >= n) return;
    ns[i] = 1.0f / sqrtf(fmaxf((float)outdeg[i], 1.0f));
    nd[i] = 1.0f / sqrtf(fmaxf((float)indeg[i], 1.0f));
}

// ---- wave-64 inclusive scan helper ----
static __device__ __forceinline__ int wave_incl_scan(int x, int lane) {
#pragma unroll
    for (int off = 1; off < 64; off <<= 1) {
        int y = __shfl_up(x, off, 64);
        if (lane >= off) x += y;
    }
    return x;
}

// ---- per-block exclusive scan; emits block totals ----
__global__ void scan_block_kernel(const int* __restrict__ in, int* __restrict__ out,
                                  int* __restrict__ bsums, int n) {
    __shared__ int wsum[4];
    int i = blockIdx.x * 256 + threadIdx.x;
    int lane = threadIdx.x & 63, wid = threadIdx.x >> 6;
    int v = (i < n) ? in[i] : 0;
    int sc = wave_incl_scan(v, lane);
    if (lane == 63) wsum[wid] = sc;
    __syncthreads();
    int add = 0;
    for (int w = 0; w < wid; ++w) add += wsum[w];
    if (i < n) out[i] = sc - v + add;
    if (threadIdx.x == 255) bsums[blockIdx.x] = sc + add;
}

// ---- single-block exclusive scan of block sums (in-place), any nb ----
__global__ void scan_sums_kernel(int* __restrict__ bsums, int nb) {
    __shared__ int wsum[4];
    __shared__ int carry;
    int lane = threadIdx.x & 63, wid = threadIdx.x >> 6;
    if (threadIdx.x == 0) carry = 0;
    __syncthreads();
    for (int base = 0; base < nb; base += 256) {
        int i = base + threadIdx.x;
        int v = (i < nb) ? bsums[i] : 0;
        int sc = wave_incl_scan(v, lane);
        if (lane == 63) wsum[wid] = sc;
        __syncthreads();
        int add = carry;
        for (int w = 0; w < wid; ++w) add += wsum[w];
        if (i < nb) bsums[i] = sc - v + add;
        __syncthreads();
        if (threadIdx.x == 0) carry += wsum[0] + wsum[1] + wsum[2] + wsum[3];
        __syncthreads();
    }
}

// ---- add scanned block offsets; set rowptr[n] = E ----
__global__ void add_offsets_kernel(int* __restrict__ rowptr, const int* __restrict__ bsums,
                                   int n, int E) {
    int i = blockIdx.x * 256 + threadIdx.x;
    if (i < n) rowptr[i] += bsums[i >> 8];
    if (i == 0) rowptr[n] = E;
}

__global__ void copy_int_kernel(const int* __restrict__ in, int* __restrict__ out, int n) {
    int i = blockIdx.x * 256 + threadIdx.x;
    if (i < n) out[i] = in[i];
}

// ---- counting-sort fill: csr_src[rowptr[dst] + k] = src ----
__global__ void fill_kernel(const int* __restrict__ src, const int* __restrict__ dst,
                            int* __restrict__ cursor, int* __restrict__ csr_src, int E) {
    int e = blockIdx.x * 256 + threadIdx.x;
    if (e >= E) return;
    int pos = atomicAdd(&cursor[dst[e]], 1);
    csr_src[pos] = src[e];
}

// ---- pull-mode gather: out[node] = act( nd[node] * sum_{e in in(node)} t[src[e]] + bias ) ----
// One wave per node; WIDTH=128 -> float2/lane, WIDTH=64 -> float/lane.
template <int WIDTH, bool RELU, bool BIAS>
__global__ __launch_bounds__(256) void gather_kernel(
    const float* __restrict__ t, const int* __restrict__ rowptr,
    const int* __restrict__ csr_src, const float* __restrict__ nd,
    const float* __restrict__ bias, float* __restrict__ out, int N) {
    int node = blockIdx.x * 4 + (threadIdx.x >> 6);
    if (node >= N) return;
    int lane = threadIdx.x & 63;
    int beg = rowptr[node], end = rowptr[node + 1];
    if (WIDTH == 128) {
        const float2* tp = reinterpret_cast<const float2*>(t);
        float ax = 0.f, ay = 0.f;
        for (int e = beg; e < end; ++e) {
            int s = csr_src[e];
            float2 v = tp[(size_t)s * 64 + lane];
            ax += v.x; ay += v.y;
        }
        float sc = nd[node];
        float rx = ax * sc, ry = ay * sc;
        if (BIAS) { rx += bias[2 * lane]; ry += bias[2 * lane + 1]; }
        if (RELU) { rx = fmaxf(rx, 0.f); ry = fmaxf(ry, 0.f); }
        float2 r; r.x = rx; r.y = ry;
        reinterpret_cast<float2*>(out)[(size_t)node * 64 + lane] = r;
    } else {
        float acc = 0.f;
        for (int e = beg; e < end; ++e) {
            int s = csr_src[e];
            acc += t[(size_t)s * 64 + lane];
        }
        float r = acc * nd[node];
        if (BIAS) r += bias[lane];
        if (RELU) r = fmaxf(r, 0.f);
        out[(size_t)node * 64 + lane] = r;
    }
}

// ---- dense GEMM: out[row][c] = (A[row] . W[:,c]) * scale[row]  (+bias, relu optional) ----
template <int DOUT, bool RELU, bool BIAS>
__global__ __launch_bounds__(256) void gemm_kernel(
    const float* __restrict__ A, const float* __restrict__ W, const float* __restrict__ bias,
    const float* __restrict__ scale, float* __restrict__ out, int n) {
    constexpr int CPT = DOUT / 4;        // cols per thread (32 or 16)
    constexpr int KT = 64;               // k-tile
    constexpr int RS = KT * CPT + 8;     // f32 units per region; byte stride % 128 == 32
    __shared__ __align__(16) float Wl[4 * RS];
    __shared__ float bl[DOUT];

    if (BIAS && threadIdx.x < DOUT) bl[threadIdx.x] = bias[threadIdx.x];

    int row = blockIdx.x * 64 + (threadIdx.x >> 2);
    int rc = min(row, n - 1);            // clamp so all threads reach barriers
    int g = threadIdx.x & 3;
    const float* a = A + (size_t)rc * DIN;
    const float* wg = Wl + g * RS;

    float acc[CPT];
#pragma unroll
    for (int c = 0; c < CPT; ++c) acc[c] = 0.f;

    for (int k0 = 0; k0 < DIN; k0 += KT) {
        __syncthreads();
        for (int i = threadIdx.x; i < KT * DOUT; i += 256) {
            int kk = i / DOUT, c = i % DOUT;
            Wl[(c / CPT) * RS + kk * CPT + (c % CPT)] = W[(size_t)(k0 + kk) * DOUT + c];
        }
        __syncthreads();

#pragma unroll 4
        for (int kk = 0; kk < KT; kk += 4) {
            float4 av = *reinterpret_cast<const float4*>(a + k0 + kk);
#pragma unroll
            for (int t = 0; t < 4; ++t) {
                float aval = (&av.x)[t];
                const float4* wp = reinterpret_cast<const float4*>(wg + (kk + t) * CPT);
#pragma unroll
                for (int q = 0; q < CPT / 4; ++q) {
                    float4 wv = wp[q];
                    acc[q * 4 + 0] = fmaf(aval, wv.x, acc[q * 4 + 0]);
                    acc[q * 4 + 1] = fmaf(aval, wv.y, acc[q * 4 + 1]);
                    acc[q * 4 + 2] = fmaf(aval, wv.z, acc[q * 4 + 2]);
                    acc[q * 4 + 3] = fmaf(aval, wv.w, acc[q * 4 + 3]);
                }
            }
        }
    }

    if (row < n) {
        float sc = scale[row];
        float* op = out + (size_t)row * DOUT + g * CPT;
#pragma unroll
        for (int c = 0; c < CPT; ++c) {
            float v = acc[c] * sc;
            if (BIAS) v += bl[g * CPT + c];
            if (RELU) v = fmaxf(v, 0.f);
            op[c] = v;
        }
    }
}

extern "C" void kernel_launch(void* const* d_in, const int* in_sizes, int n_in,
                              void* d_out, int out_size, void* d_ws, size_t ws_size,
                              hipStream_t stream) {
    const float* feature = (const float*)d_in[0];
    const int*   src     = (const int*)d_in[1];
    const int*   dst     = (const int*)d_in[2];
    const float* W1      = (const float*)d_in[3];
    const float* b1      = (const float*)d_in[4];
    const float* W2      = (const float*)d_in[5];
    const float* b2      = (const float*)d_in[6];

    const int N = in_sizes[0] / DIN;
    const int E = in_sizes[1];
    const int nb = (N + 255) / 256;

    char* ws = (char*)d_ws;
    size_t off = 0;
    auto take = [&](size_t bytes) -> void* {
        void* p = ws + off;
        off += (bytes + 255) & ~(size_t)255;
        return p;
    };
    int*   outdeg  = (int*)take((size_t)N * 4);
    int*   indeg   = (int*)take((size_t)N * 4);
    float* ns      = (float*)take((size_t)N * 4);
    float* nd      = (float*)take((size_t)N * 4);
    int*   rowptr  = (int*)take((size_t)(N + 1) * 4);
    int*   cursor  = (int*)take((size_t)N * 4);
    int*   bsums   = (int*)take((size_t)nb * 4);
    int*   csr_src = (int*)take((size_t)E * 4);
    float* t1      = (float*)take((size_t)N * DIN * 4);  // reused as t2 (N*64)
    float* h2      = (float*)take((size_t)N * DIN * 4);

    hipMemsetAsync(outdeg, 0, (size_t)N * 4, stream);
    hipMemsetAsync(indeg,  0, (size_t)N * 4, stream);

    // degrees + norms
    deg_kernel<<<(E + 255) / 256, 256, 0, stream>>>(src, dst, outdeg, indeg, E);
    norm_kernel<<<(N + 255) / 256, 256, 0, stream>>>(outdeg, indeg, ns, nd, N);

    // CSR by dst: rowptr = exscan(indeg); csr_src = counting sort
    scan_block_kernel<<<nb, 256, 0, stream>>>(indeg, rowptr, bsums, N);
    scan_sums_kernel<<<1, 256, 0, stream>>>(bsums, nb);
    add_offsets_kernel<<<nb, 256, 0, stream>>>(rowptr, bsums, N, E);
    copy_int_kernel<<<nb, 256, 0, stream>>>(rowptr, cursor, N);
    fill_kernel<<<(E + 255) / 256, 256, 0, stream>>>(src, dst, cursor, csr_src, E);

    // Layer 1 (GEMM-first): t1 = (X @ W1) * ns ; h2 = relu(gather(t1) * nd + b1)
    gemm_kernel<128, false, false><<<(N + 63) / 64, 256, 0, stream>>>(feature, W1, nullptr, ns, t1, N);
    gather_kernel<128, true, true><<<(N + 3) / 4, 256, 0, stream>>>(t1, rowptr, csr_src, nd, b1, h2, N);

    // Layer 2: t2 = (h2 @ W2) * ns ; out = gather(t2) * nd + b2
    gemm_kernel<64, false, false><<<(N + 63) / 64, 256, 0, stream>>>(h2, W2, nullptr, ns, t1, N);
    gather_kernel<64, false, true><<<(N + 3) / 4, 256, 0, stream>>>(t1, rowptr, csr_src, nd, b2, (float*)d_out, N);
}

// Round 4
// 579.026 us; speedup vs baseline: 9.7074x; 1.1999x over previous
//
#include <hip/hip_runtime.h>

#define DIN 128
typedef unsigned short u16;
typedef unsigned int u32;

static __device__ __forceinline__ float bf2f(u32 lo16) {
    union { u32 u; float f; } c;
    c.u = lo16 << 16;
    return c.f;
}
static __device__ __forceinline__ u32 f2bf(float f) {
    union { float f; u32 u; } c;
    c.f = f;
    u32 u = c.u;
    u += 0x7fffu + ((u >> 16) & 1u);   // RTNE
    return u >> 16;
}

// ---- degree counting ----
__global__ void deg_kernel(const int* __restrict__ src, const int* __restrict__ dst,
                           int* __restrict__ outdeg, int* __restrict__ indeg, int E) {
    int i = blockIdx.x * blockDim.x + threadIdx.x;
    if (i >= E) return;
    atomicAdd(&outdeg[src[i]], 1);
    atomicAdd(&indeg[dst[i]], 1);
}

// ---- norms: 1/sqrt(max(deg,1)) ----
__global__ void norm_kernel(const int* __restrict__ outdeg, const int* __restrict__ indeg,
                            float* __restrict__ ns, float* __restrict__ nd, int n) {
    int i = blockIdx.x * blockDim.x + threadIdx.x;
    if (i >= n) return;
    ns[i] = 1.0f / sqrtf(fmaxf((float)outdeg[i], 1.0f));
    nd[i] = 1.0f / sqrtf(fmaxf((float)indeg[i], 1.0f));
}

// ---- wave-64 inclusive scan helper ----
static __device__ __forceinline__ int wave_incl_scan(int x, int lane) {
#pragma unroll
    for (int off = 1; off < 64; off <<= 1) {
        int y = __shfl_up(x, off, 64);
        if (lane >= off) x += y;
    }
    return x;
}

// ---- per-block exclusive scan; emits block totals ----
__global__ void scan_block_kernel(const int* __restrict__ in, int* __restrict__ out,
                                  int* __restrict__ bsums, int n) {
    __shared__ int wsum[4];
    int i = blockIdx.x * 256 + threadIdx.x;
    int lane = threadIdx.x & 63, wid = threadIdx.x >> 6;
    int v = (i < n) ? in[i] : 0;
    int sc = wave_incl_scan(v, lane);
    if (lane == 63) wsum[wid] = sc;
    __syncthreads();
    int add = 0;
    for (int w = 0; w < wid; ++w) add += wsum[w];
    if (i < n) out[i] = sc - v + add;
    if (threadIdx.x == 255) bsums[blockIdx.x] = sc + add;
}

// ---- single-block exclusive scan of block sums (in-place) ----
__global__ void scan_sums_kernel(int* __restrict__ bsums, int nb) {
    __shared__ int wsum[4];
    __shared__ int carry;
    int lane = threadIdx.x & 63, wid = threadIdx.x >> 6;
    if (threadIdx.x == 0) carry = 0;
    __syncthreads();
    for (int base = 0; base < nb; base += 256) {
        int i = base + threadIdx.x;
        int v = (i < nb) ? bsums[i] : 0;
        int sc = wave_incl_scan(v, lane);
        if (lane == 63) wsum[wid] = sc;
        __syncthreads();
        int add = carry;
        for (int w = 0; w < wid; ++w) add += wsum[w];
        if (i < nb) bsums[i] = sc - v + add;
        __syncthreads();
        if (threadIdx.x == 0) carry += wsum[0] + wsum[1] + wsum[2] + wsum[3];
        __syncthreads();
    }
}

// ---- add scanned block offsets; init cursor; set rowptr[n] = E ----
__global__ void add_offsets_kernel(int* __restrict__ rowptr, int* __restrict__ cursor,
                                   const int* __restrict__ bsums, int n, int E) {
    int i = blockIdx.x * 256 + threadIdx.x;
    if (i < n) {
        int v = rowptr[i] + bsums[i >> 8];
        rowptr[i] = v;
        cursor[i] = v;
    }
    if (i == 0) rowptr[n] = E;
}

// ---- counting-sort fill: csr_src[rowptr[dst] + k] = src ----
__global__ void fill_kernel(const int* __restrict__ src, const int* __restrict__ dst,
                            int* __restrict__ cursor, int* __restrict__ csr_src, int E) {
    int e = blockIdx.x * 256 + threadIdx.x;
    if (e >= E) return;
    int pos = atomicAdd(&cursor[dst[e]], 1);
    csr_src[pos] = src[e];
}

// ---- gather (layer 1): h2 = relu(nd * sum t1[src] + b1), t1/h2 bf16 128-wide ----
__global__ __launch_bounds__(256) void gather128_kernel(
    const u32* __restrict__ t, const int* __restrict__ rowptr,
    const int* __restrict__ csr_src, const float* __restrict__ nd,
    const float* __restrict__ bias, u32* __restrict__ out, int N) {
    int node = blockIdx.x * 4 + (threadIdx.x >> 6);
    if (node >= N) return;
    int lane = threadIdx.x & 63;
    int beg = rowptr[node], end = rowptr[node + 1];
    float ax = 0.f, ay = 0.f;
    int e = beg;
    for (; e + 1 < end; e += 2) {
        int s0 = csr_src[e], s1 = csr_src[e + 1];
        u32 v0 = t[(size_t)s0 * 64 + lane];
        u32 v1 = t[(size_t)s1 * 64 + lane];
        ax += bf2f(v0 & 0xffffu) + bf2f(v1 & 0xffffu);
        ay += bf2f(v0 >> 16) + bf2f(v1 >> 16);
    }
    if (e < end) {
        u32 v0 = t[(size_t)csr_src[e] * 64 + lane];
        ax += bf2f(v0 & 0xffffu);
        ay += bf2f(v0 >> 16);
    }
    float sc = nd[node];
    float rx = fmaxf(ax * sc + bias[2 * lane], 0.f);
    float ry = fmaxf(ay * sc + bias[2 * lane + 1], 0.f);
    out[(size_t)node * 64 + lane] = f2bf(rx) | (f2bf(ry) << 16);
}

// ---- gather (layer 2): out = nd * sum t2[src] + b2, t2 bf16 64-wide, out f32 ----
__global__ __launch_bounds__(256) void gather64_kernel(
    const u16* __restrict__ t, const int* __restrict__ rowptr,
    const int* __restrict__ csr_src, const float* __restrict__ nd,
    const float* __restrict__ bias, float* __restrict__ out, int N) {
    int node = blockIdx.x * 4 + (threadIdx.x >> 6);
    if (node >= N) return;
    int lane = threadIdx.x & 63;
    int beg = rowptr[node], end = rowptr[node + 1];
    float acc = 0.f;
    int e = beg;
    for (; e + 1 < end; e += 2) {
        int s0 = csr_src[e], s1 = csr_src[e + 1];
        float v0 = bf2f((u32)t[(size_t)s0 * 64 + lane]);
        float v1 = bf2f((u32)t[(size_t)s1 * 64 + lane]);
        acc += v0 + v1;
    }
    if (e < end) acc += bf2f((u32)t[(size_t)csr_src[e] * 64 + lane]);
    out[(size_t)node * 64 + lane] = acc * nd[node] + bias[lane];
}

// ---- dense GEMM: out[row][c] = (A[row] . W[:,c]) * scale[row] -> bf16 ----
// A is f32 (ABF16=false) or bf16 (ABF16=true); W f32; out bf16 packed.
template <int DOUT, bool ABF16>
__global__ __launch_bounds__(256) void gemm_kernel(
    const void* __restrict__ Av, const float* __restrict__ W,
    const float* __restrict__ scale, u16* __restrict__ out, int n) {
    constexpr int CPT = DOUT / 4;        // cols per thread (32 or 16)
    constexpr int KT = 64;               // k-tile
    constexpr int RS = KT * CPT + 8;     // f32 units per region; byte stride % 128 == 32
    __shared__ __align__(16) float Wl[4 * RS];

    int row = blockIdx.x * 64 + (threadIdx.x >> 2);
    int rc = min(row, n - 1);            // clamp so all threads reach barriers
    int g = threadIdx.x & 3;
    const float* wg = Wl + g * RS;

    float acc[CPT];
#pragma unroll
    for (int c = 0; c < CPT; ++c) acc[c] = 0.f;

    for (int k0 = 0; k0 < DIN; k0 += KT) {
        __syncthreads();
        for (int i = threadIdx.x; i < KT * DOUT; i += 256) {
            int kk = i / DOUT, c = i % DOUT;
            Wl[(c / CPT) * RS + kk * CPT + (c % CPT)] = W[(size_t)(k0 + kk) * DOUT + c];
        }
        __syncthreads();

#pragma unroll 4
        for (int kk = 0; kk < KT; kk += 4) {
            float a4[4];
            if (ABF16) {
                uint2 av = *reinterpret_cast<const uint2*>(
                    (const u16*)Av + (size_t)rc * DIN + k0 + kk);
                a4[0] = bf2f(av.x & 0xffffu); a4[1] = bf2f(av.x >> 16);
                a4[2] = bf2f(av.y & 0xffffu); a4[3] = bf2f(av.y >> 16);
            } else {
                float4 av = *reinterpret_cast<const float4*>(
                    (const float*)Av + (size_t)rc * DIN + k0 + kk);
                a4[0] = av.x; a4[1] = av.y; a4[2] = av.z; a4[3] = av.w;
            }
#pragma unroll
            for (int t = 0; t < 4; ++t) {
                float aval = a4[t];
                const float4* wp = reinterpret_cast<const float4*>(wg + (kk + t) * CPT);
#pragma unroll
                for (int q = 0; q < CPT / 4; ++q) {
                    float4 wv = wp[q];
                    acc[q * 4 + 0] = fmaf(aval, wv.x, acc[q * 4 + 0]);
                    acc[q * 4 + 1] = fmaf(aval, wv.y, acc[q * 4 + 1]);
                    acc[q * 4 + 2] = fmaf(aval, wv.z, acc[q * 4 + 2]);
                    acc[q * 4 + 3] = fmaf(aval, wv.w, acc[q * 4 + 3]);
                }
            }
        }
    }

    if (row < n) {
        float sc = scale[row];
        u32 pk[CPT / 2];
#pragma unroll
        for (int c = 0; c < CPT; c += 2) {
            pk[c / 2] = f2bf(acc[c] * sc) | (f2bf(acc[c + 1] * sc) << 16);
        }
        u32* op = reinterpret_cast<u32*>(out + (size_t)row * DOUT + g * CPT);
#pragma unroll
        for (int q = 0; q < CPT / 8; ++q) {
            uint4 v;
            v.x = pk[q * 4 + 0]; v.y = pk[q * 4 + 1];
            v.z = pk[q * 4 + 2]; v.w = pk[q * 4 + 3];
            reinterpret_cast<uint4*>(op)[q] = v;
        }
    }
}

extern "C" void kernel_launch(void* const* d_in, const int* in_sizes, int n_in,
                              void* d_out, int out_size, void* d_ws, size_t ws_size,
                              hipStream_t stream) {
    const float* feature = (const float*)d_in[0];
    const int*   src     = (const int*)d_in[1];
    const int*   dst     = (const int*)d_in[2];
    const float* W1      = (const float*)d_in[3];
    const float* b1      = (const float*)d_in[4];
    const float* W2      = (const float*)d_in[5];
    const float* b2      = (const float*)d_in[6];

    const int N = in_sizes[0] / DIN;
    const int E = in_sizes[1];
    const int nb = (N + 255) / 256;

    char* ws = (char*)d_ws;
    size_t off = 0;
    auto take = [&](size_t bytes) -> void* {
        void* p = ws + off;
        off += (bytes + 255) & ~(size_t)255;
        return p;
    };
    int*   outdeg  = (int*)take((size_t)N * 4);
    int*   indeg   = (int*)take((size_t)N * 4);
    float* ns      = (float*)take((size_t)N * 4);
    float* nd      = (float*)take((size_t)N * 4);
    int*   rowptr  = (int*)take((size_t)(N + 1) * 4);
    int*   cursor  = (int*)take((size_t)N * 4);
    int*   bsums   = (int*)take((size_t)nb * 4);
    int*   csr_src = (int*)take((size_t)E * 4);
    u16*   t1      = (u16*)take((size_t)N * DIN * 2);  // also reused as t2 (N*64 bf16)
    u16*   h2      = (u16*)take((size_t)N * DIN * 2);

    hipMemsetAsync(outdeg, 0, (size_t)N * 4, stream);
    hipMemsetAsync(indeg,  0, (size_t)N * 4, stream);

    // degrees + norms
    deg_kernel<<<(E + 255) / 256, 256, 0, stream>>>(src, dst, outdeg, indeg, E);
    norm_kernel<<<(N + 255) / 256, 256, 0, stream>>>(outdeg, indeg, ns, nd, N);

    // CSR by dst
    scan_block_kernel<<<nb, 256, 0, stream>>>(indeg, rowptr, bsums, N);
    scan_sums_kernel<<<1, 256, 0, stream>>>(bsums, nb);
    add_offsets_kernel<<<nb, 256, 0, stream>>>(rowptr, cursor, bsums, N, E);
    fill_kernel<<<(E + 255) / 256, 256, 0, stream>>>(src, dst, cursor, csr_src, E);

    // Layer 1: t1 = bf16((X @ W1) * ns); h2 = bf16(relu(gather(t1) * nd + b1))
    gemm_kernel<128, false><<<(N + 63) / 64, 256, 0, stream>>>(feature, W1, ns, t1, N);
    gather128_kernel<<<(N + 3) / 4, 256, 0, stream>>>(
        (const u32*)t1, rowptr, csr_src, nd, b1, (u32*)h2, N);

    // Layer 2: t2 = bf16((h2 @ W2) * ns); out = gather(t2) * nd + b2 (f32)
    gemm_kernel<64, true><<<(N + 63) / 64, 256, 0, stream>>>(h2, W2, ns, t1, N);
    gather64_kernel<<<(N + 3) / 4, 256, 0, stream>>>(
        t1, rowptr, csr_src, nd, b2, (float*)d_out, N);
}

// Round 5
// 401.303 us; speedup vs baseline: 14.0065x; 1.4429x over previous
//
#include <hip/hip_runtime.h>

#define DIN 128
#define PB 512            // partition blocks
typedef unsigned short u16;
typedef unsigned int u32;

static __device__ __forceinline__ float bf2f(u32 lo16) {
    union { u32 u; float f; } c;
    c.u = lo16 << 16;
    return c.f;
}
static __device__ __forceinline__ u32 f2bf(float f) {
    union { float f; u32 u; } c;
    c.f = f;
    u32 u = c.u;
    u += 0x7fffu + ((u >> 16) & 1u);   // RTNE
    return u >> 16;
}

// ---- wave-64 inclusive scan helper ----
static __device__ __forceinline__ int wave_incl_scan(int x, int lane) {
#pragma unroll
    for (int off = 1; off < 64; off <<= 1) {
        int y = __shfl_up(x, off, 64);
        if (lane >= off) x += y;
    }
    return x;
}

// ---- pass 1: per-block bucket histograms of dst>>8 and src>>8 ----
__global__ __launch_bounds__(256) void hist_kernel(
    const int* __restrict__ src, const int* __restrict__ dst,
    u32* __restrict__ matd, u32* __restrict__ mats, int E, int NB) {
    __shared__ u32 hd[512], hs[512];
    int t = threadIdx.x, b = blockIdx.x;
    for (int j = t; j < NB; j += 256) { hd[j] = 0; hs[j] = 0; }
    __syncthreads();
    int chunk = (E + PB - 1) / PB;
    int s = b * chunk, e = min(E, s + chunk);
    for (int i = s + t; i < e; i += 256) {
        atomicAdd(&hd[((u32)dst[i]) >> 8], 1u);
        atomicAdd(&hs[((u32)src[i]) >> 8], 1u);
    }
    __syncthreads();
    for (int j = t; j < NB; j += 256) {
        matd[(size_t)j * PB + b] = hd[j];
        mats[(size_t)j * PB + b] = hs[j];
    }
}

// ---- per-block exclusive scan; emits block totals ----
__global__ void scan_block_kernel(const int* __restrict__ in, int* __restrict__ out,
                                  int* __restrict__ bsums, int n) {
    __shared__ int wsum[4];
    int i = blockIdx.x * 256 + threadIdx.x;
    int lane = threadIdx.x & 63, wid = threadIdx.x >> 6;
    int v = (i < n) ? in[i] : 0;
    int sc = wave_incl_scan(v, lane);
    if (lane == 63) wsum[wid] = sc;
    __syncthreads();
    int add = 0;
    for (int w = 0; w < wid; ++w) add += wsum[w];
    if (i < n) out[i] = sc - v + add;
    if (threadIdx.x == 255) bsums[blockIdx.x] = sc + add;
}

// ---- single-block exclusive scan of block sums (in-place) ----
__global__ void scan_sums_kernel(int* __restrict__ bsums, int nb) {
    __shared__ int wsum[4];
    __shared__ int carry;
    int lane = threadIdx.x & 63, wid = threadIdx.x >> 6;
    if (threadIdx.x == 0) carry = 0;
    __syncthreads();
    for (int base = 0; base < nb; base += 256) {
        int i = base + threadIdx.x;
        int v = (i < nb) ? bsums[i] : 0;
        int sc = wave_incl_scan(v, lane);
        if (lane == 63) wsum[wid] = sc;
        __syncthreads();
        int add = carry;
        for (int w = 0; w < wid; ++w) add += wsum[w];
        if (i < nb) bsums[i] = sc - v + add;
        __syncthreads();
        if (threadIdx.x == 0) carry += wsum[0] + wsum[1] + wsum[2] + wsum[3];
        __syncthreads();
    }
}

// ---- add scanned block offsets (plain exscan finalize) ----
__global__ void add_off2_kernel(int* __restrict__ out, const int* __restrict__ bsums, int n) {
    int i = blockIdx.x * 256 + threadIdx.x;
    if (i < n) out[i] += bsums[i >> 8];
}

// ---- pass 2: partition edges into bucket-contiguous arrays (LDS cursors, plain stores) ----
__global__ __launch_bounds__(256) void part_kernel(
    const int* __restrict__ src, const int* __restrict__ dst,
    const int* __restrict__ offd, const int* __restrict__ offs,
    u32* __restrict__ part_dst, u32* __restrict__ part_src, int E, int NB) {
    __shared__ u32 cd[512], cs[512];
    int t = threadIdx.x, b = blockIdx.x;
    for (int j = t; j < NB; j += 256) {
        cd[j] = (u32)offd[(size_t)j * PB + b];
        cs[j] = (u32)offs[(size_t)j * PB + b];
    }
    __syncthreads();
    int chunk = (E + PB - 1) / PB;
    int s = b * chunk, e = min(E, s + chunk);
    for (int i = s + t; i < e; i += 256) {
        u32 dv = (u32)dst[i], sv = (u32)src[i];
        u32 p = atomicAdd(&cd[dv >> 8], 1u);
        part_dst[p] = ((dv & 255u) << 24) | sv;
        u32 q = atomicAdd(&cs[sv >> 8], 1u);
        part_src[q] = sv;
    }
}

// ---- pass 3: per-bucket exact build: rowptr, nd, csr_src, ns ----
__global__ __launch_bounds__(256) void build_kernel(
    const u32* __restrict__ part_dst, const u32* __restrict__ part_src,
    const int* __restrict__ offd, const int* __restrict__ offs,
    int* __restrict__ rowptr, float* __restrict__ nd, float* __restrict__ ns,
    int* __restrict__ csr_src, int N, int E, int NB) {
    __shared__ u32 lh[256];
    __shared__ u32 cur[256];
    __shared__ int wsum[4];
    int t = threadIdx.x, k = blockIdx.x;
    int lane = t & 63, wid = t >> 6;
    int node = k * 256 + t;

    int beg = offd[(size_t)k * PB];
    int end = (k + 1 < NB) ? offd[(size_t)(k + 1) * PB] : E;

    lh[t] = 0;
    __syncthreads();
    for (int i = beg + t; i < end; i += 256)
        atomicAdd(&lh[part_dst[i] >> 24], 1u);
    __syncthreads();

    int cnt = (int)lh[t];
    int sc = wave_incl_scan(cnt, lane);
    if (lane == 63) wsum[wid] = sc;
    __syncthreads();
    int add = 0;
    for (int w = 0; w < wid; ++w) add += wsum[w];
    int ex = sc - cnt + add;

    if (node < N) {
        rowptr[node] = beg + ex;
        nd[node] = rsqrtf(fmaxf((float)cnt, 1.0f));
    }
    if (k == 0 && t == 0) rowptr[N] = E;
    cur[t] = (u32)(beg + ex);
    __syncthreads();

    for (int i = beg + t; i < end; i += 256) {
        u32 v = part_dst[i];
        u32 pos = atomicAdd(&cur[v >> 24], 1u);
        csr_src[pos] = (int)(v & 0xFFFFFFu);
    }

    // src side: exact outdeg histogram -> ns
    int beg2 = offs[(size_t)k * PB];
    int end2 = (k + 1 < NB) ? offs[(size_t)(k + 1) * PB] : E;
    __syncthreads();
    lh[t] = 0;
    __syncthreads();
    for (int i = beg2 + t; i < end2; i += 256)
        atomicAdd(&lh[part_src[i] & 255u], 1u);
    __syncthreads();
    if (node < N) ns[node] = rsqrtf(fmaxf((float)lh[t], 1.0f));
}

// ---- gather (layer 1): h2 = relu(nd * sum t1[src] + b1), t1/h2 bf16 128-wide ----
__global__ __launch_bounds__(256) void gather128_kernel(
    const u32* __restrict__ t, const int* __restrict__ rowptr,
    const int* __restrict__ csr_src, const float* __restrict__ nd,
    const float* __restrict__ bias, u32* __restrict__ out, int N) {
    int node = blockIdx.x * 4 + (threadIdx.x >> 6);
    if (node >= N) return;
    int lane = threadIdx.x & 63;
    int beg = rowptr[node], end = rowptr[node + 1];
    float ax = 0.f, ay = 0.f;
    int e = beg;
    for (; e + 1 < end; e += 2) {
        int s0 = csr_src[e], s1 = csr_src[e + 1];
        u32 v0 = t[(size_t)s0 * 64 + lane];
        u32 v1 = t[(size_t)s1 * 64 + lane];
        ax += bf2f(v0 & 0xffffu) + bf2f(v1 & 0xffffu);
        ay += bf2f(v0 >> 16) + bf2f(v1 >> 16);
    }
    if (e < end) {
        u32 v0 = t[(size_t)csr_src[e] * 64 + lane];
        ax += bf2f(v0 & 0xffffu);
        ay += bf2f(v0 >> 16);
    }
    float sc = nd[node];
    float rx = fmaxf(ax * sc + bias[2 * lane], 0.f);
    float ry = fmaxf(ay * sc + bias[2 * lane + 1], 0.f);
    out[(size_t)node * 64 + lane] = f2bf(rx) | (f2bf(ry) << 16);
}

// ---- gather (layer 2): out = nd * sum t2[src] + b2, t2 bf16 64-wide, out f32 ----
__global__ __launch_bounds__(256) void gather64_kernel(
    const u16* __restrict__ t, const int* __restrict__ rowptr,
    const int* __restrict__ csr_src, const float* __restrict__ nd,
    const float* __restrict__ bias, float* __restrict__ out, int N) {
    int node = blockIdx.x * 4 + (threadIdx.x >> 6);
    if (node >= N) return;
    int lane = threadIdx.x & 63;
    int beg = rowptr[node], end = rowptr[node + 1];
    float acc = 0.f;
    int e = beg;
    for (; e + 1 < end; e += 2) {
        int s0 = csr_src[e], s1 = csr_src[e + 1];
        float v0 = bf2f((u32)t[(size_t)s0 * 64 + lane]);
        float v1 = bf2f((u32)t[(size_t)s1 * 64 + lane]);
        acc += v0 + v1;
    }
    if (e < end) acc += bf2f((u32)t[(size_t)csr_src[e] * 64 + lane]);
    out[(size_t)node * 64 + lane] = acc * nd[node] + bias[lane];
}

// ---- dense GEMM: out[row][c] = (A[row] . W[:,c]) * scale[row] -> bf16 ----
template <int DOUT, bool ABF16>
__global__ __launch_bounds__(256) void gemm_kernel(
    const void* __restrict__ Av, const float* __restrict__ W,
    const float* __restrict__ scale, u16* __restrict__ out, int n) {
    constexpr int CPT = DOUT / 4;
    constexpr int KT = 64;
    constexpr int RS = KT * CPT + 8;
    __shared__ __align__(16) float Wl[4 * RS];

    int row = blockIdx.x * 64 + (threadIdx.x >> 2);
    int rc = min(row, n - 1);
    int g = threadIdx.x & 3;
    const float* wg = Wl + g * RS;

    float acc[CPT];
#pragma unroll
    for (int c = 0; c < CPT; ++c) acc[c] = 0.f;

    for (int k0 = 0; k0 < DIN; k0 += KT) {
        __syncthreads();
        for (int i = threadIdx.x; i < KT * DOUT; i += 256) {
            int kk = i / DOUT, c = i % DOUT;
            Wl[(c / CPT) * RS + kk * CPT + (c % CPT)] = W[(size_t)(k0 + kk) * DOUT + c];
        }
        __syncthreads();

#pragma unroll 4
        for (int kk = 0; kk < KT; kk += 4) {
            float a4[4];
            if (ABF16) {
                uint2 av = *reinterpret_cast<const uint2*>(
                    (const u16*)Av + (size_t)rc * DIN + k0 + kk);
                a4[0] = bf2f(av.x & 0xffffu); a4[1] = bf2f(av.x >> 16);
                a4[2] = bf2f(av.y & 0xffffu); a4[3] = bf2f(av.y >> 16);
            } else {
                float4 av = *reinterpret_cast<const float4*>(
                    (const float*)Av + (size_t)rc * DIN + k0 + kk);
                a4[0] = av.x; a4[1] = av.y; a4[2] = av.z; a4[3] = av.w;
            }
#pragma unroll
            for (int t = 0; t < 4; ++t) {
                float aval = a4[t];
                const float4* wp = reinterpret_cast<const float4*>(wg + (kk + t) * CPT);
#pragma unroll
                for (int q = 0; q < CPT / 4; ++q) {
                    float4 wv = wp[q];
                    acc[q * 4 + 0] = fmaf(aval, wv.x, acc[q * 4 + 0]);
                    acc[q * 4 + 1] = fmaf(aval, wv.y, acc[q * 4 + 1]);
                    acc[q * 4 + 2] = fmaf(aval, wv.z, acc[q * 4 + 2]);
                    acc[q * 4 + 3] = fmaf(aval, wv.w, acc[q * 4 + 3]);
                }
            }
        }
    }

    if (row < n) {
        float sc = scale[row];
        u32 pk[CPT / 2];
#pragma unroll
        for (int c = 0; c < CPT; c += 2) {
            pk[c / 2] = f2bf(acc[c] * sc) | (f2bf(acc[c + 1] * sc) << 16);
        }
        u32* op = reinterpret_cast<u32*>(out + (size_t)row * DOUT + g * CPT);
#pragma unroll
        for (int q = 0; q < CPT / 8; ++q) {
            uint4 v;
            v.x = pk[q * 4 + 0]; v.y = pk[q * 4 + 1];
            v.z = pk[q * 4 + 2]; v.w = pk[q * 4 + 3];
            reinterpret_cast<uint4*>(op)[q] = v;
        }
    }
}

extern "C" void kernel_launch(void* const* d_in, const int* in_sizes, int n_in,
                              void* d_out, int out_size, void* d_ws, size_t ws_size,
                              hipStream_t stream) {
    const float* feature = (const float*)d_in[0];
    const int*   src     = (const int*)d_in[1];
    const int*   dst     = (const int*)d_in[2];
    const float* W1      = (const float*)d_in[3];
    const float* b1      = (const float*)d_in[4];
    const float* W2      = (const float*)d_in[5];
    const float* b2      = (const float*)d_in[6];

    const int N = in_sizes[0] / DIN;
    const int E = in_sizes[1];
    const int NB = (N + 255) >> 8;            // dst/src buckets (<=512 for N<=131072)
    const int M = NB * PB;                    // count-matrix size
    const int nbm = (M + 255) / 256;

    char* ws = (char*)d_ws;
    size_t off = 0;
    auto take = [&](size_t bytes) -> void* {
        void* p = ws + off;
        off += (bytes + 255) & ~(size_t)255;
        return p;
    };
    float* ns       = (float*)take((size_t)N * 4);
    float* nd       = (float*)take((size_t)N * 4);
    int*   rowptr   = (int*)take((size_t)(N + 1) * 4);
    int*   csr_src  = (int*)take((size_t)E * 4);
    u32*   matd     = (u32*)take((size_t)M * 4);
    u32*   mats     = (u32*)take((size_t)M * 4);
    int*   offd     = (int*)take((size_t)M * 4);
    int*   offs     = (int*)take((size_t)M * 4);
    int*   bs1      = (int*)take((size_t)(nbm + 4) * 4);
    int*   bs2      = (int*)take((size_t)(nbm + 4) * 4);
    u32*   part_dst = (u32*)take((size_t)E * 4);
    u32*   part_src = (u32*)take((size_t)E * 4);
    u16*   t1       = (u16*)take((size_t)N * DIN * 2);  // reused as t2 (N*64 bf16)
    u16*   h2       = (u16*)take((size_t)N * DIN * 2);

    // CSR build: hist -> scan x2 -> partition -> per-bucket build (no global atomics)
    hist_kernel<<<PB, 256, 0, stream>>>(src, dst, matd, mats, E, NB);
    scan_block_kernel<<<nbm, 256, 0, stream>>>((const int*)matd, offd, bs1, M);
    scan_sums_kernel<<<1, 256, 0, stream>>>(bs1, nbm);
    add_off2_kernel<<<nbm, 256, 0, stream>>>(offd, bs1, M);
    scan_block_kernel<<<nbm, 256, 0, stream>>>((const int*)mats, offs, bs2, M);
    scan_sums_kernel<<<1, 256, 0, stream>>>(bs2, nbm);
    add_off2_kernel<<<nbm, 256, 0, stream>>>(offs, bs2, M);
    part_kernel<<<PB, 256, 0, stream>>>(src, dst, offd, offs, part_dst, part_src, E, NB);
    build_kernel<<<NB, 256, 0, stream>>>(part_dst, part_src, offd, offs,
                                         rowptr, nd, ns, csr_src, N, E, NB);

    // Layer 1: t1 = bf16((X @ W1) * ns); h2 = bf16(relu(gather(t1) * nd + b1))
    gemm_kernel<128, false><<<(N + 63) / 64, 256, 0, stream>>>(feature, W1, ns, t1, N);
    gather128_kernel<<<(N + 3) / 4, 256, 0, stream>>>(
        (const u32*)t1, rowptr, csr_src, nd, b1, (u32*)h2, N);

    // Layer 2: t2 = bf16((h2 @ W2) * ns); out = gather(t2) * nd + b2 (f32)
    gemm_kernel<64, true><<<(N + 63) / 64, 256, 0, stream>>>(h2, W2, ns, t1, N);
    gather64_kernel<<<(N + 3) / 4, 256, 0, stream>>>(
        t1, rowptr, csr_src, nd, b2, (float*)d_out, N);
}

// Round 6
// 310.212 us; speedup vs baseline: 18.1194x; 1.2936x over previous
//
#include <hip/hip_runtime.h>

#define DIN 128
#define PB 512            // partition blocks
typedef unsigned short u16;
typedef unsigned int u32;
typedef __attribute__((ext_vector_type(8))) short bf16x8;  // 8 bf16 (4 VGPRs)
typedef __attribute__((ext_vector_type(4))) float f32x4;   // 4 f32 acc

static __device__ __forceinline__ float bf2f(u32 lo16) {
    union { u32 u; float f; } c;
    c.u = lo16 << 16;
    return c.f;
}
static __device__ __forceinline__ u32 f2bf(float f) {
    union { float f; u32 u; } c;
    c.f = f;
    u32 u = c.u;
    u += 0x7fffu + ((u >> 16) & 1u);   // RTNE
    return u >> 16;
}

// ---- wave-64 inclusive scan helper ----
static __device__ __forceinline__ int wave_incl_scan(int x, int lane) {
#pragma unroll
    for (int off = 1; off < 64; off <<= 1) {
        int y = __shfl_up(x, off, 64);
        if (lane >= off) x += y;
    }
    return x;
}

// ---- pass 1: per-block bucket histograms of dst>>8 and src>>8 ----
__global__ __launch_bounds__(256) void hist_kernel(
    const int* __restrict__ src, const int* __restrict__ dst,
    u32* __restrict__ matd, u32* __restrict__ mats, int E, int NB) {
    __shared__ u32 hd[512], hs[512];
    int t = threadIdx.x, b = blockIdx.x;
    for (int j = t; j < NB; j += 256) { hd[j] = 0; hs[j] = 0; }
    __syncthreads();
    int chunk = (E + PB - 1) / PB;
    int s = b * chunk, e = min(E, s + chunk);
    for (int i = s + t; i < e; i += 256) {
        atomicAdd(&hd[((u32)dst[i]) >> 8], 1u);
        atomicAdd(&hs[((u32)src[i]) >> 8], 1u);
    }
    __syncthreads();
    for (int j = t; j < NB; j += 256) {
        matd[(size_t)j * PB + b] = hd[j];
        mats[(size_t)j * PB + b] = hs[j];
    }
}

// ---- per-block exclusive scan; emits block totals ----
__global__ void scan_block_kernel(const int* __restrict__ in, int* __restrict__ out,
                                  int* __restrict__ bsums, int n) {
    __shared__ int wsum[4];
    int i = blockIdx.x * 256 + threadIdx.x;
    int lane = threadIdx.x & 63, wid = threadIdx.x >> 6;
    int v = (i < n) ? in[i] : 0;
    int sc = wave_incl_scan(v, lane);
    if (lane == 63) wsum[wid] = sc;
    __syncthreads();
    int add = 0;
    for (int w = 0; w < wid; ++w) add += wsum[w];
    if (i < n) out[i] = sc - v + add;
    if (threadIdx.x == 255) bsums[blockIdx.x] = sc + add;
}

// ---- single-block exclusive scan of block sums (in-place) ----
__global__ void scan_sums_kernel(int* __restrict__ bsums, int nb) {
    __shared__ int wsum[4];
    __shared__ int carry;
    int lane = threadIdx.x & 63, wid = threadIdx.x >> 6;
    if (threadIdx.x == 0) carry = 0;
    __syncthreads();
    for (int base = 0; base < nb; base += 256) {
        int i = base + threadIdx.x;
        int v = (i < nb) ? bsums[i] : 0;
        int sc = wave_incl_scan(v, lane);
        if (lane == 63) wsum[wid] = sc;
        __syncthreads();
        int add = carry;
        for (int w = 0; w < wid; ++w) add += wsum[w];
        if (i < nb) bsums[i] = sc - v + add;
        __syncthreads();
        if (threadIdx.x == 0) carry += wsum[0] + wsum[1] + wsum[2] + wsum[3];
        __syncthreads();
    }
}

// ---- add scanned block offsets (plain exscan finalize) ----
__global__ void add_off2_kernel(int* __restrict__ out, const int* __restrict__ bsums, int n) {
    int i = blockIdx.x * 256 + threadIdx.x;
    if (i < n) out[i] += bsums[i >> 8];
}

// ---- pass 2: partition edges into bucket-contiguous arrays (LDS cursors, plain stores) ----
__global__ __launch_bounds__(256) void part_kernel(
    const int* __restrict__ src, const int* __restrict__ dst,
    const int* __restrict__ offd, const int* __restrict__ offs,
    u32* __restrict__ part_dst, u32* __restrict__ part_src, int E, int NB) {
    __shared__ u32 cd[512], cs[512];
    int t = threadIdx.x, b = blockIdx.x;
    for (int j = t; j < NB; j += 256) {
        cd[j] = (u32)offd[(size_t)j * PB + b];
        cs[j] = (u32)offs[(size_t)j * PB + b];
    }
    __syncthreads();
    int chunk = (E + PB - 1) / PB;
    int s = b * chunk, e = min(E, s + chunk);
    for (int i = s + t; i < e; i += 256) {
        u32 dv = (u32)dst[i], sv = (u32)src[i];
        u32 p = atomicAdd(&cd[dv >> 8], 1u);
        part_dst[p] = ((dv & 255u) << 24) | sv;
        u32 q = atomicAdd(&cs[sv >> 8], 1u);
        part_src[q] = sv;
    }
}

// ---- pass 3: per-bucket exact build: rowptr, nd, csr_src, ns ----
__global__ __launch_bounds__(256) void build_kernel(
    const u32* __restrict__ part_dst, const u32* __restrict__ part_src,
    const int* __restrict__ offd, const int* __restrict__ offs,
    int* __restrict__ rowptr, float* __restrict__ nd, float* __restrict__ ns,
    int* __restrict__ csr_src, int N, int E, int NB) {
    __shared__ u32 lh[256];
    __shared__ u32 cur[256];
    __shared__ int wsum[4];
    int t = threadIdx.x, k = blockIdx.x;
    int lane = t & 63, wid = t >> 6;
    int node = k * 256 + t;

    int beg = offd[(size_t)k * PB];
    int end = (k + 1 < NB) ? offd[(size_t)(k + 1) * PB] : E;

    lh[t] = 0;
    __syncthreads();
    for (int i = beg + t; i < end; i += 256)
        atomicAdd(&lh[part_dst[i] >> 24], 1u);
    __syncthreads();

    int cnt = (int)lh[t];
    int sc = wave_incl_scan(cnt, lane);
    if (lane == 63) wsum[wid] = sc;
    __syncthreads();
    int add = 0;
    for (int w = 0; w < wid; ++w) add += wsum[w];
    int ex = sc - cnt + add;

    if (node < N) {
        rowptr[node] = beg + ex;
        nd[node] = rsqrtf(fmaxf((float)cnt, 1.0f));
    }
    if (k == 0 && t == 0) rowptr[N] = E;
    cur[t] = (u32)(beg + ex);
    __syncthreads();

    for (int i = beg + t; i < end; i += 256) {
        u32 v = part_dst[i];
        u32 pos = atomicAdd(&cur[v >> 24], 1u);
        csr_src[pos] = (int)(v & 0xFFFFFFu);
    }

    // src side: exact outdeg histogram -> ns
    int beg2 = offs[(size_t)k * PB];
    int end2 = (k + 1 < NB) ? offs[(size_t)(k + 1) * PB] : E;
    __syncthreads();
    lh[t] = 0;
    __syncthreads();
    for (int i = beg2 + t; i < end2; i += 256)
        atomicAdd(&lh[part_src[i] & 255u], 1u);
    __syncthreads();
    if (node < N) ns[node] = rsqrtf(fmaxf((float)lh[t], 1.0f));
}

// ---- gather (layer 1): h2 = relu(nd * sum t1[src] + b1), t1/h2 bf16 128-wide ----
__global__ __launch_bounds__(256) void gather128_kernel(
    const u32* __restrict__ t, const int* __restrict__ rowptr,
    const int* __restrict__ csr_src, const float* __restrict__ nd,
    const float* __restrict__ bias, u32* __restrict__ out, int N) {
    int node = blockIdx.x * 4 + (threadIdx.x >> 6);
    if (node >= N) return;
    int lane = threadIdx.x & 63;
    int beg = rowptr[node], end = rowptr[node + 1];
    float ax = 0.f, ay = 0.f;
    int e = beg;
    for (; e + 1 < end; e += 2) {
        int s0 = csr_src[e], s1 = csr_src[e + 1];
        u32 v0 = t[(size_t)s0 * 64 + lane];
        u32 v1 = t[(size_t)s1 * 64 + lane];
        ax += bf2f(v0 & 0xffffu) + bf2f(v1 & 0xffffu);
        ay += bf2f(v0 >> 16) + bf2f(v1 >> 16);
    }
    if (e < end) {
        u32 v0 = t[(size_t)csr_src[e] * 64 + lane];
        ax += bf2f(v0 & 0xffffu);
        ay += bf2f(v0 >> 16);
    }
    float sc = nd[node];
    float rx = fmaxf(ax * sc + bias[2 * lane], 0.f);
    float ry = fmaxf(ay * sc + bias[2 * lane + 1], 0.f);
    out[(size_t)node * 64 + lane] = f2bf(rx) | (f2bf(ry) << 16);
}

// ---- gather (layer 2): out = nd * sum t2[src] + b2, t2 bf16 64-wide, out f32 ----
__global__ __launch_bounds__(256) void gather64_kernel(
    const u16* __restrict__ t, const int* __restrict__ rowptr,
    const int* __restrict__ csr_src, const float* __restrict__ nd,
    const float* __restrict__ bias, float* __restrict__ out, int N) {
    int node = blockIdx.x * 4 + (threadIdx.x >> 6);
    if (node >= N) return;
    int lane = threadIdx.x & 63;
    int beg = rowptr[node], end = rowptr[node + 1];
    float acc = 0.f;
    int e = beg;
    for (; e + 1 < end; e += 2) {
        int s0 = csr_src[e], s1 = csr_src[e + 1];
        float v0 = bf2f((u32)t[(size_t)s0 * 64 + lane]);
        float v1 = bf2f((u32)t[(size_t)s1 * 64 + lane]);
        acc += v0 + v1;
    }
    if (e < end) acc += bf2f((u32)t[(size_t)csr_src[e] * 64 + lane]);
    out[(size_t)node * 64 + lane] = acc * nd[node] + bias[lane];
}

// ---- MFMA GEMM: out[row][:] = bf16( (A[row] @ W) * scale[row] ), W f32 [DIN][DOUT] ----
// 4 waves/block, 64 rows/block, wave = 16 rows x DOUT cols.
// Swapped operands: acc = mfma(Wt_frag, A_frag, acc) computes C^T tile, so each
// lane ends with row = lane&15, cols = ct*16 + (lane>>4)*4 + [0..3] -> 8B stores.
// Wt staged in LDS bf16 [DOUT][136]: byte stride 272 -> bank stride 4, max 2-way (free).
template <int DOUT, bool ABF16>
__global__ __launch_bounds__(256) void gemm_mfma_kernel(
    const void* __restrict__ Av, const float* __restrict__ W,
    const float* __restrict__ scale, u16* __restrict__ out, int n) {
    constexpr int NT = DOUT / 16;       // col tiles
    constexpr int WK = DIN + 8;        // padded k-stride in bf16 units
    __shared__ u16 Wt[DOUT * WK];

    // stage W^T as bf16: Wt[c][k] = bf16(W[k][c]); coalesced f32 reads
    for (int i = threadIdx.x; i < DIN * DOUT; i += 256) {
        int k = i / DOUT, c = i % DOUT;
        Wt[c * WK + k] = (u16)f2bf(W[i]);
    }

    int lane = threadIdx.x & 63;
    int wid = threadIdx.x >> 6;
    int row = blockIdx.x * 64 + wid * 16 + (lane & 15);
    int rc = min(row, n - 1);
    int kg = lane >> 4;                 // k-group 0..3

    // A fragments: afrag[s] covers k = s*32 + kg*8 + [0..7] of row rc
    bf16x8 afrag[4];
    if (ABF16) {
        const u16* ap = (const u16*)Av + (size_t)rc * DIN + kg * 8;
#pragma unroll
        for (int s = 0; s < 4; ++s) {
            uint4 v = *reinterpret_cast<const uint4*>(ap + s * 32);
            afrag[s] = *reinterpret_cast<bf16x8*>(&v);
        }
    } else {
        const float* ap = (const float*)Av + (size_t)rc * DIN + kg * 8;
#pragma unroll
        for (int s = 0; s < 4; ++s) {
            float4 v0 = *reinterpret_cast<const float4*>(ap + s * 32);
            float4 v1 = *reinterpret_cast<const float4*>(ap + s * 32 + 4);
            uint4 v;
            v.x = f2bf(v0.x) | (f2bf(v0.y) << 16);
            v.y = f2bf(v0.z) | (f2bf(v0.w) << 16);
            v.z = f2bf(v1.x) | (f2bf(v1.y) << 16);
            v.w = f2bf(v1.z) | (f2bf(v1.w) << 16);
            afrag[s] = *reinterpret_cast<bf16x8*>(&v);
        }
    }

    f32x4 acc[NT];
#pragma unroll
    for (int t = 0; t < NT; ++t) acc[t] = (f32x4){0.f, 0.f, 0.f, 0.f};

    __syncthreads();                    // Wt ready

#pragma unroll
    for (int t = 0; t < NT; ++t) {
        const u16* wp = Wt + (t * 16 + (lane & 15)) * WK + kg * 8;
#pragma unroll
        for (int s = 0; s < 4; ++s) {
            uint4 wv = *reinterpret_cast<const uint4*>(wp + s * 32);
            bf16x8 wfrag = *reinterpret_cast<bf16x8*>(&wv);
            acc[t] = __builtin_amdgcn_mfma_f32_16x16x32_bf16(wfrag, afrag[s], acc[t], 0, 0, 0);
        }
    }

    if (row < n) {
        float sc = scale[row];
        u16* op = out + (size_t)row * DOUT + kg * 4;
#pragma unroll
        for (int t = 0; t < NT; ++t) {
            uint2 v;
            v.x = f2bf(acc[t][0] * sc) | (f2bf(acc[t][1] * sc) << 16);
            v.y = f2bf(acc[t][2] * sc) | (f2bf(acc[t][3] * sc) << 16);
            *reinterpret_cast<uint2*>(op + t * 16) = v;
        }
    }
}

extern "C" void kernel_launch(void* const* d_in, const int* in_sizes, int n_in,
                              void* d_out, int out_size, void* d_ws, size_t ws_size,
                              hipStream_t stream) {
    const float* feature = (const float*)d_in[0];
    const int*   src     = (const int*)d_in[1];
    const int*   dst     = (const int*)d_in[2];
    const float* W1      = (const float*)d_in[3];
    const float* b1      = (const float*)d_in[4];
    const float* W2      = (const float*)d_in[5];
    const float* b2      = (const float*)d_in[6];

    const int N = in_sizes[0] / DIN;
    const int E = in_sizes[1];
    const int NB = (N + 255) >> 8;            // dst/src buckets (<=512 for N<=131072)
    const int M = NB * PB;                    // count-matrix size
    const int nbm = (M + 255) / 256;

    char* ws = (char*)d_ws;
    size_t off = 0;
    auto take = [&](size_t bytes) -> void* {
        void* p = ws + off;
        off += (bytes + 255) & ~(size_t)255;
        return p;
    };
    float* ns       = (float*)take((size_t)N * 4);
    float* nd       = (float*)take((size_t)N * 4);
    int*   rowptr   = (int*)take((size_t)(N + 1) * 4);
    int*   csr_src  = (int*)take((size_t)E * 4);
    u32*   matd     = (u32*)take((size_t)M * 4);
    u32*   mats     = (u32*)take((size_t)M * 4);
    int*   offd     = (int*)take((size_t)M * 4);
    int*   offs     = (int*)take((size_t)M * 4);
    int*   bs1      = (int*)take((size_t)(nbm + 4) * 4);
    int*   bs2      = (int*)take((size_t)(nbm + 4) * 4);
    u32*   part_dst = (u32*)take((size_t)E * 4);
    u32*   part_src = (u32*)take((size_t)E * 4);
    u16*   t1       = (u16*)take((size_t)N * DIN * 2);  // reused as t2 (N*64 bf16)
    u16*   h2       = (u16*)take((size_t)N * DIN * 2);

    // CSR build: hist -> scan x2 -> partition -> per-bucket build (no global atomics)
    hist_kernel<<<PB, 256, 0, stream>>>(src, dst, matd, mats, E, NB);
    scan_block_kernel<<<nbm, 256, 0, stream>>>((const int*)matd, offd, bs1, M);
    scan_sums_kernel<<<1, 256, 0, stream>>>(bs1, nbm);
    add_off2_kernel<<<nbm, 256, 0, stream>>>(offd, bs1, M);
    scan_block_kernel<<<nbm, 256, 0, stream>>>((const int*)mats, offs, bs2, M);
    scan_sums_kernel<<<1, 256, 0, stream>>>(bs2, nbm);
    add_off2_kernel<<<nbm, 256, 0, stream>>>(offs, bs2, M);
    part_kernel<<<PB, 256, 0, stream>>>(src, dst, offd, offs, part_dst, part_src, E, NB);
    build_kernel<<<NB, 256, 0, stream>>>(part_dst, part_src, offd, offs,
                                         rowptr, nd, ns, csr_src, N, E, NB);

    // Layer 1: t1 = bf16((X @ W1) * ns); h2 = bf16(relu(gather(t1) * nd + b1))
    gemm_mfma_kernel<128, false><<<(N + 63) / 64, 256, 0, stream>>>(feature, W1, ns, t1, N);
    gather128_kernel<<<(N + 3) / 4, 256, 0, stream>>>(
        (const u32*)t1, rowptr, csr_src, nd, b1, (u32*)h2, N);

    // Layer 2: t2 = bf16((h2 @ W2) * ns); out = gather(t2) * nd + b2 (f32)
    gemm_mfma_kernel<64, true><<<(N + 63) / 64, 256, 0, stream>>>(h2, W2, ns, t1, N);
    gather64_kernel<<<(N + 3) / 4, 256, 0, stream>>>(
        t1, rowptr, csr_src, nd, b2, (float*)d_out, N);
}

// Round 7
// 230.930 us; speedup vs baseline: 24.3400x; 1.3433x over previous
//
#include <hip/hip_runtime.h>

#define DIN 128
#define PB 512            // partition blocks
typedef unsigned short u16;
typedef unsigned int u32;
typedef __attribute__((ext_vector_type(8))) short bf16x8;  // 8 bf16 (4 VGPRs)
typedef __attribute__((ext_vector_type(4))) float f32x4;   // 4 f32 acc

static __device__ __forceinline__ float bf2f(u32 lo16) {
    union { u32 u; float f; } c;
    c.u = lo16 << 16;
    return c.f;
}
static __device__ __forceinline__ u32 f2bf(float f) {
    union { float f; u32 u; } c;
    c.f = f;
    u32 u = c.u;
    u += 0x7fffu + ((u >> 16) & 1u);   // RTNE
    return u >> 16;
}

// ---- wave-64 inclusive scan helper ----
static __device__ __forceinline__ int wave_incl_scan(int x, int lane) {
#pragma unroll
    for (int off = 1; off < 64; off <<= 1) {
        int y = __shfl_up(x, off, 64);
        if (lane >= off) x += y;
    }
    return x;
}

// ---- pass 1: per-block bucket histograms of dst>>8 and src>>8 ----
__global__ __launch_bounds__(256) void hist_kernel(
    const int* __restrict__ src, const int* __restrict__ dst,
    u32* __restrict__ matd, u32* __restrict__ mats, int E, int NB) {
    __shared__ u32 hd[512], hs[512];
    int t = threadIdx.x, b = blockIdx.x;
    for (int j = t; j < NB; j += 256) { hd[j] = 0; hs[j] = 0; }
    __syncthreads();
    int chunk = (E + PB - 1) / PB;
    int s = b * chunk, e = min(E, s + chunk);
    for (int i = s + t; i < e; i += 256) {
        atomicAdd(&hd[((u32)dst[i]) >> 8], 1u);
        atomicAdd(&hs[((u32)src[i]) >> 8], 1u);
    }
    __syncthreads();
    for (int j = t; j < NB; j += 256) {
        matd[(size_t)j * PB + b] = hd[j];
        mats[(size_t)j * PB + b] = hs[j];
    }
}

// ---- per-block exclusive scan; emits block totals ----
__global__ void scan_block_kernel(const int* __restrict__ in, int* __restrict__ out,
                                  int* __restrict__ bsums, int n) {
    __shared__ int wsum[4];
    int i = blockIdx.x * 256 + threadIdx.x;
    int lane = threadIdx.x & 63, wid = threadIdx.x >> 6;
    int v = (i < n) ? in[i] : 0;
    int sc = wave_incl_scan(v, lane);
    if (lane == 63) wsum[wid] = sc;
    __syncthreads();
    int add = 0;
    for (int w = 0; w < wid; ++w) add += wsum[w];
    if (i < n) out[i] = sc - v + add;
    if (threadIdx.x == 255) bsums[blockIdx.x] = sc + add;
}

// ---- single-block exclusive scan of block sums (in-place) ----
__global__ void scan_sums_kernel(int* __restrict__ bsums, int nb) {
    __shared__ int wsum[4];
    __shared__ int carry;
    int lane = threadIdx.x & 63, wid = threadIdx.x >> 6;
    if (threadIdx.x == 0) carry = 0;
    __syncthreads();
    for (int base = 0; base < nb; base += 256) {
        int i = base + threadIdx.x;
        int v = (i < nb) ? bsums[i] : 0;
        int sc = wave_incl_scan(v, lane);
        if (lane == 63) wsum[wid] = sc;
        __syncthreads();
        int add = carry;
        for (int w = 0; w < wid; ++w) add += wsum[w];
        if (i < nb) bsums[i] = sc - v + add;
        __syncthreads();
        if (threadIdx.x == 0) carry += wsum[0] + wsum[1] + wsum[2] + wsum[3];
        __syncthreads();
    }
}

// ---- add scanned block offsets (plain exscan finalize) ----
__global__ void add_off2_kernel(int* __restrict__ out, const int* __restrict__ bsums, int n) {
    int i = blockIdx.x * 256 + threadIdx.x;
    if (i < n) out[i] += bsums[i >> 8];
}

// ---- pass 2: partition edges into bucket-contiguous arrays (LDS cursors, plain stores) ----
__global__ __launch_bounds__(256) void part_kernel(
    const int* __restrict__ src, const int* __restrict__ dst,
    const int* __restrict__ offd, const int* __restrict__ offs,
    u32* __restrict__ part_dst, u32* __restrict__ part_src, int E, int NB) {
    __shared__ u32 cd[512], cs[512];
    int t = threadIdx.x, b = blockIdx.x;
    for (int j = t; j < NB; j += 256) {
        cd[j] = (u32)offd[(size_t)j * PB + b];
        cs[j] = (u32)offs[(size_t)j * PB + b];
    }
    __syncthreads();
    int chunk = (E + PB - 1) / PB;
    int s = b * chunk, e = min(E, s + chunk);
    for (int i = s + t; i < e; i += 256) {
        u32 dv = (u32)dst[i], sv = (u32)src[i];
        u32 p = atomicAdd(&cd[dv >> 8], 1u);
        part_dst[p] = ((dv & 255u) << 24) | sv;
        u32 q = atomicAdd(&cs[sv >> 8], 1u);
        part_src[q] = sv;
    }
}

// ---- pass 3: per-bucket exact build: rowptr, nd, csr_src, ns ----
__global__ __launch_bounds__(256) void build_kernel(
    const u32* __restrict__ part_dst, const u32* __restrict__ part_src,
    const int* __restrict__ offd, const int* __restrict__ offs,
    int* __restrict__ rowptr, float* __restrict__ nd, float* __restrict__ ns,
    int* __restrict__ csr_src, int N, int E, int NB) {
    __shared__ u32 lh[256];
    __shared__ u32 cur[256];
    __shared__ int wsum[4];
    int t = threadIdx.x, k = blockIdx.x;
    int lane = t & 63, wid = t >> 6;
    int node = k * 256 + t;

    int beg = offd[(size_t)k * PB];
    int end = (k + 1 < NB) ? offd[(size_t)(k + 1) * PB] : E;

    lh[t] = 0;
    __syncthreads();
    for (int i = beg + t; i < end; i += 256)
        atomicAdd(&lh[part_dst[i] >> 24], 1u);
    __syncthreads();

    int cnt = (int)lh[t];
    int sc = wave_incl_scan(cnt, lane);
    if (lane == 63) wsum[wid] = sc;
    __syncthreads();
    int add = 0;
    for (int w = 0; w < wid; ++w) add += wsum[w];
    int ex = sc - cnt + add;

    if (node < N) {
        rowptr[node] = beg + ex;
        nd[node] = rsqrtf(fmaxf((float)cnt, 1.0f));
    }
    if (k == 0 && t == 0) rowptr[N] = E;
    cur[t] = (u32)(beg + ex);
    __syncthreads();

    for (int i = beg + t; i < end; i += 256) {
        u32 v = part_dst[i];
        u32 pos = atomicAdd(&cur[v >> 24], 1u);
        csr_src[pos] = (int)(v & 0xFFFFFFu);
    }

    // src side: exact outdeg histogram -> ns
    int beg2 = offs[(size_t)k * PB];
    int end2 = (k + 1 < NB) ? offs[(size_t)(k + 1) * PB] : E;
    __syncthreads();
    lh[t] = 0;
    __syncthreads();
    for (int i = beg2 + t; i < end2; i += 256)
        atomicAdd(&lh[part_src[i] & 255u], 1u);
    __syncthreads();
    if (node < N) ns[node] = rsqrtf(fmaxf((float)lh[t], 1.0f));
}

// ---- gather (layer 1): h2 = relu(nd * sum t1[src] + b1), t1/h2 bf16 128-wide ----
// 8/4/2/1 unroll ladder: 8 independent row loads in flight per wave (MLP=8).
__global__ __launch_bounds__(256) void gather128_kernel(
    const u32* __restrict__ t, const int* __restrict__ rowptr,
    const int* __restrict__ csr_src, const float* __restrict__ nd,
    const float* __restrict__ bias, u32* __restrict__ out, int N) {
    int node = blockIdx.x * 4 + (threadIdx.x >> 6);
    if (node >= N) return;
    int lane = threadIdx.x & 63;
    int beg = rowptr[node], end = rowptr[node + 1];
    float ax = 0.f, ay = 0.f;
    int e = beg;
    for (; e + 8 <= end; e += 8) {
        int s[8]; u32 v[8];
#pragma unroll
        for (int j = 0; j < 8; ++j) s[j] = csr_src[e + j];
#pragma unroll
        for (int j = 0; j < 8; ++j) v[j] = t[(size_t)s[j] * 64 + lane];
#pragma unroll
        for (int j = 0; j < 8; ++j) { ax += bf2f(v[j] & 0xffffu); ay += bf2f(v[j] >> 16); }
    }
    if (e + 4 <= end) {
        int s[4]; u32 v[4];
#pragma unroll
        for (int j = 0; j < 4; ++j) s[j] = csr_src[e + j];
#pragma unroll
        for (int j = 0; j < 4; ++j) v[j] = t[(size_t)s[j] * 64 + lane];
#pragma unroll
        for (int j = 0; j < 4; ++j) { ax += bf2f(v[j] & 0xffffu); ay += bf2f(v[j] >> 16); }
        e += 4;
    }
    if (e + 2 <= end) {
        int s0 = csr_src[e], s1 = csr_src[e + 1];
        u32 v0 = t[(size_t)s0 * 64 + lane];
        u32 v1 = t[(size_t)s1 * 64 + lane];
        ax += bf2f(v0 & 0xffffu) + bf2f(v1 & 0xffffu);
        ay += bf2f(v0 >> 16) + bf2f(v1 >> 16);
        e += 2;
    }
    if (e < end) {
        u32 v0 = t[(size_t)csr_src[e] * 64 + lane];
        ax += bf2f(v0 & 0xffffu);
        ay += bf2f(v0 >> 16);
    }
    float sc = nd[node];
    float rx = fmaxf(ax * sc + bias[2 * lane], 0.f);
    float ry = fmaxf(ay * sc + bias[2 * lane + 1], 0.f);
    out[(size_t)node * 64 + lane] = f2bf(rx) | (f2bf(ry) << 16);
}

// ---- gather (layer 2): out = nd * sum t2[src] + b2, t2 bf16 64-wide, out f32 ----
__global__ __launch_bounds__(256) void gather64_kernel(
    const u16* __restrict__ t, const int* __restrict__ rowptr,
    const int* __restrict__ csr_src, const float* __restrict__ nd,
    const float* __restrict__ bias, float* __restrict__ out, int N) {
    int node = blockIdx.x * 4 + (threadIdx.x >> 6);
    if (node >= N) return;
    int lane = threadIdx.x & 63;
    int beg = rowptr[node], end = rowptr[node + 1];
    float acc = 0.f;
    int e = beg;
    for (; e + 8 <= end; e += 8) {
        int s[8]; u16 v[8];
#pragma unroll
        for (int j = 0; j < 8; ++j) s[j] = csr_src[e + j];
#pragma unroll
        for (int j = 0; j < 8; ++j) v[j] = t[(size_t)s[j] * 64 + lane];
#pragma unroll
        for (int j = 0; j < 8; ++j) acc += bf2f((u32)v[j]);
    }
    if (e + 4 <= end) {
        int s[4]; u16 v[4];
#pragma unroll
        for (int j = 0; j < 4; ++j) s[j] = csr_src[e + j];
#pragma unroll
        for (int j = 0; j < 4; ++j) v[j] = t[(size_t)s[j] * 64 + lane];
#pragma unroll
        for (int j = 0; j < 4; ++j) acc += bf2f((u32)v[j]);
        e += 4;
    }
    if (e + 2 <= end) {
        int s0 = csr_src[e], s1 = csr_src[e + 1];
        float v0 = bf2f((u32)t[(size_t)s0 * 64 + lane]);
        float v1 = bf2f((u32)t[(size_t)s1 * 64 + lane]);
        acc += v0 + v1;
        e += 2;
    }
    if (e < end) acc += bf2f((u32)t[(size_t)csr_src[e] * 64 + lane]);
    out[(size_t)node * 64 + lane] = acc * nd[node] + bias[lane];
}

// ---- MFMA GEMM: out[row][:] = bf16( (A[row] @ W) * scale[row] ), W f32 [DIN][DOUT] ----
template <int DOUT, bool ABF16>
__global__ __launch_bounds__(256) void gemm_mfma_kernel(
    const void* __restrict__ Av, const float* __restrict__ W,
    const float* __restrict__ scale, u16* __restrict__ out, int n) {
    constexpr int NT = DOUT / 16;       // col tiles
    constexpr int WK = DIN + 8;        // padded k-stride in bf16 units
    __shared__ u16 Wt[DOUT * WK];

    for (int i = threadIdx.x; i < DIN * DOUT; i += 256) {
        int k = i / DOUT, c = i % DOUT;
        Wt[c * WK + k] = (u16)f2bf(W[i]);
    }

    int lane = threadIdx.x & 63;
    int wid = threadIdx.x >> 6;
    int row = blockIdx.x * 64 + wid * 16 + (lane & 15);
    int rc = min(row, n - 1);
    int kg = lane >> 4;                 // k-group 0..3

    bf16x8 afrag[4];
    if (ABF16) {
        const u16* ap = (const u16*)Av + (size_t)rc * DIN + kg * 8;
#pragma unroll
        for (int s = 0; s < 4; ++s) {
            uint4 v = *reinterpret_cast<const uint4*>(ap + s * 32);
            afrag[s] = *reinterpret_cast<bf16x8*>(&v);
        }
    } else {
        const float* ap = (const float*)Av + (size_t)rc * DIN + kg * 8;
#pragma unroll
        for (int s = 0; s < 4; ++s) {
            float4 v0 = *reinterpret_cast<const float4*>(ap + s * 32);
            float4 v1 = *reinterpret_cast<const float4*>(ap + s * 32 + 4);
            uint4 v;
            v.x = f2bf(v0.x) | (f2bf(v0.y) << 16);
            v.y = f2bf(v0.z) | (f2bf(v0.w) << 16);
            v.z = f2bf(v1.x) | (f2bf(v1.y) << 16);
            v.w = f2bf(v1.z) | (f2bf(v1.w) << 16);
            afrag[s] = *reinterpret_cast<bf16x8*>(&v);
        }
    }

    f32x4 acc[NT];
#pragma unroll
    for (int t = 0; t < NT; ++t) acc[t] = (f32x4){0.f, 0.f, 0.f, 0.f};

    __syncthreads();                    // Wt ready

#pragma unroll
    for (int t = 0; t < NT; ++t) {
        const u16* wp = Wt + (t * 16 + (lane & 15)) * WK + kg * 8;
#pragma unroll
        for (int s = 0; s < 4; ++s) {
            uint4 wv = *reinterpret_cast<const uint4*>(wp + s * 32);
            bf16x8 wfrag = *reinterpret_cast<bf16x8*>(&wv);
            acc[t] = __builtin_amdgcn_mfma_f32_16x16x32_bf16(wfrag, afrag[s], acc[t], 0, 0, 0);
        }
    }

    if (row < n) {
        float sc = scale[row];
        u16* op = out + (size_t)row * DOUT + kg * 4;
#pragma unroll
        for (int t = 0; t < NT; ++t) {
            uint2 v;
            v.x = f2bf(acc[t][0] * sc) | (f2bf(acc[t][1] * sc) << 16);
            v.y = f2bf(acc[t][2] * sc) | (f2bf(acc[t][3] * sc) << 16);
            *reinterpret_cast<uint2*>(op + t * 16) = v;
        }
    }
}

extern "C" void kernel_launch(void* const* d_in, const int* in_sizes, int n_in,
                              void* d_out, int out_size, void* d_ws, size_t ws_size,
                              hipStream_t stream) {
    const float* feature = (const float*)d_in[0];
    const int*   src     = (const int*)d_in[1];
    const int*   dst     = (const int*)d_in[2];
    const float* W1      = (const float*)d_in[3];
    const float* b1      = (const float*)d_in[4];
    const float* W2      = (const float*)d_in[5];
    const float* b2      = (const float*)d_in[6];

    const int N = in_sizes[0] / DIN;
    const int E = in_sizes[1];
    const int NB = (N + 255) >> 8;            // dst/src buckets (<=512 for N<=131072)
    const int M = NB * PB;                    // count-matrix size
    const int nbm = (M + 255) / 256;

    char* ws = (char*)d_ws;
    size_t off = 0;
    auto take = [&](size_t bytes) -> void* {
        void* p = ws + off;
        off += (bytes + 255) & ~(size_t)255;
        return p;
    };
    float* ns       = (float*)take((size_t)N * 4);
    float* nd       = (float*)take((size_t)N * 4);
    int*   rowptr   = (int*)take((size_t)(N + 1) * 4);
    int*   csr_src  = (int*)take((size_t)E * 4);
    u32*   matd     = (u32*)take((size_t)M * 4);
    u32*   mats     = (u32*)take((size_t)M * 4);
    int*   offd     = (int*)take((size_t)M * 4);
    int*   offs     = (int*)take((size_t)M * 4);
    int*   bs1      = (int*)take((size_t)(nbm + 4) * 4);
    int*   bs2      = (int*)take((size_t)(nbm + 4) * 4);
    u32*   part_dst = (u32*)take((size_t)E * 4);
    u32*   part_src = (u32*)take((size_t)E * 4);
    u16*   t1       = (u16*)take((size_t)N * DIN * 2);  // reused as t2 (N*64 bf16)
    u16*   h2       = (u16*)take((size_t)N * DIN * 2);

    // CSR build: hist -> scan x2 -> partition -> per-bucket build (no global atomics)
    hist_kernel<<<PB, 256, 0, stream>>>(src, dst, matd, mats, E, NB);
    scan_block_kernel<<<nbm, 256, 0, stream>>>((const int*)matd, offd, bs1, M);
    scan_sums_kernel<<<1, 256, 0, stream>>>(bs1, nbm);
    add_off2_kernel<<<nbm, 256, 0, stream>>>(offd, bs1, M);
    scan_block_kernel<<<nbm, 256, 0, stream>>>((const int*)mats, offs, bs2, M);
    scan_sums_kernel<<<1, 256, 0, stream>>>(bs2, nbm);
    add_off2_kernel<<<nbm, 256, 0, stream>>>(offs, bs2, M);
    part_kernel<<<PB, 256, 0, stream>>>(src, dst, offd, offs, part_dst, part_src, E, NB);
    build_kernel<<<NB, 256, 0, stream>>>(part_dst, part_src, offd, offs,
                                         rowptr, nd, ns, csr_src, N, E, NB);

    // Layer 1: t1 = bf16((X @ W1) * ns); h2 = bf16(relu(gather(t1) * nd + b1))
    gemm_mfma_kernel<128, false><<<(N + 63) / 64, 256, 0, stream>>>(feature, W1, ns, t1, N);
    gather128_kernel<<<(N + 3) / 4, 256, 0, stream>>>(
        (const u32*)t1, rowptr, csr_src, nd, b1, (u32*)h2, N);

    // Layer 2: t2 = bf16((h2 @ W2) * ns); out = gather(t2) * nd + b2 (f32)
    gemm_mfma_kernel<64, true><<<(N + 63) / 64, 256, 0, stream>>>(h2, W2, ns, t1, N);
    gather64_kernel<<<(N + 3) / 4, 256, 0, stream>>>(
        t1, rowptr, csr_src, nd, b2, (float*)d_out, N);
}

// Round 8
// 209.447 us; speedup vs baseline: 26.8366x; 1.1026x over previous
//
#include <hip/hip_runtime.h>

#define DIN 128
#define PB 512            // partition blocks
typedef unsigned short u16;
typedef unsigned int u32;
typedef __attribute__((ext_vector_type(8))) short bf16x8;  // 8 bf16 (4 VGPRs)
typedef __attribute__((ext_vector_type(4))) float f32x4;   // 4 f32 acc

static __device__ __forceinline__ float bf2f(u32 lo16) {
    union { u32 u; float f; } c;
    c.u = lo16 << 16;
    return c.f;
}
static __device__ __forceinline__ float bf_lo(u32 v) {
    union { u32 u; float f; } c;
    c.u = v << 16;
    return c.f;
}
static __device__ __forceinline__ float bf_hi(u32 v) {
    union { u32 u; float f; } c;
    c.u = v & 0xffff0000u;
    return c.f;
}
static __device__ __forceinline__ u32 f2bf(float f) {
    union { float f; u32 u; } c;
    c.f = f;
    u32 u = c.u;
    u += 0x7fffu + ((u >> 16) & 1u);   // RTNE
    return u >> 16;
}

// ---- wave-64 inclusive scan helper ----
static __device__ __forceinline__ int wave_incl_scan(int x, int lane) {
#pragma unroll
    for (int off = 1; off < 64; off <<= 1) {
        int y = __shfl_up(x, off, 64);
        if (lane >= off) x += y;
    }
    return x;
}

// ---- pass 1: per-block bucket histograms of dst>>8 (-> mat[0:M)) and src>>8 (-> mat[M:2M)) ----
__global__ __launch_bounds__(256) void hist_kernel(
    const int* __restrict__ src, const int* __restrict__ dst,
    u32* __restrict__ mat, int E, int NB, int M) {
    __shared__ u32 hd[512], hs[512];
    int t = threadIdx.x, b = blockIdx.x;
    for (int j = t; j < NB; j += 256) { hd[j] = 0; hs[j] = 0; }
    __syncthreads();
    int chunk = (E + PB - 1) / PB;
    int s = b * chunk, e = min(E, s + chunk);
    for (int i = s + t; i < e; i += 256) {
        atomicAdd(&hd[((u32)dst[i]) >> 8], 1u);
        atomicAdd(&hs[((u32)src[i]) >> 8], 1u);
    }
    __syncthreads();
    for (int j = t; j < NB; j += 256) {
        mat[(size_t)j * PB + b] = hd[j];
        mat[(size_t)M + (size_t)j * PB + b] = hs[j];
    }
}

// ---- per-block exclusive scan; emits block totals ----
__global__ void scan_block_kernel(const int* __restrict__ in, int* __restrict__ out,
                                  int* __restrict__ bsums, int n) {
    __shared__ int wsum[4];
    int i = blockIdx.x * 256 + threadIdx.x;
    int lane = threadIdx.x & 63, wid = threadIdx.x >> 6;
    int v = (i < n) ? in[i] : 0;
    int sc = wave_incl_scan(v, lane);
    if (lane == 63) wsum[wid] = sc;
    __syncthreads();
    int add = 0;
    for (int w = 0; w < wid; ++w) add += wsum[w];
    if (i < n) out[i] = sc - v + add;
    if (threadIdx.x == 255) bsums[blockIdx.x] = sc + add;
}

// ---- single-block exclusive scan of block sums (in-place) ----
__global__ void scan_sums_kernel(int* __restrict__ bsums, int nb) {
    __shared__ int wsum[4];
    __shared__ int carry;
    int lane = threadIdx.x & 63, wid = threadIdx.x >> 6;
    if (threadIdx.x == 0) carry = 0;
    __syncthreads();
    for (int base = 0; base < nb; base += 256) {
        int i = base + threadIdx.x;
        int v = (i < nb) ? bsums[i] : 0;
        int sc = wave_incl_scan(v, lane);
        if (lane == 63) wsum[wid] = sc;
        __syncthreads();
        int add = carry;
        for (int w = 0; w < wid; ++w) add += wsum[w];
        if (i < nb) bsums[i] = sc - v + add;
        __syncthreads();
        if (threadIdx.x == 0) carry += wsum[0] + wsum[1] + wsum[2] + wsum[3];
        __syncthreads();
    }
}

// ---- add scanned block offsets (plain exscan finalize) ----
__global__ void add_off2_kernel(int* __restrict__ out, const int* __restrict__ bsums, int n) {
    int i = blockIdx.x * 256 + threadIdx.x;
    if (i < n) out[i] += bsums[i >> 8];
}

// ---- pass 2: partition edges; part[0:E) dst-tagged, part[E:2E) src (LDS cursors) ----
__global__ __launch_bounds__(256) void part_kernel(
    const int* __restrict__ src, const int* __restrict__ dst,
    const int* __restrict__ off, u32* __restrict__ part, int E, int NB, int M) {
    __shared__ u32 cd[512], cs[512];
    int t = threadIdx.x, b = blockIdx.x;
    for (int j = t; j < NB; j += 256) {
        cd[j] = (u32)off[(size_t)j * PB + b];
        cs[j] = (u32)off[(size_t)M + (size_t)j * PB + b];
    }
    __syncthreads();
    int chunk = (E + PB - 1) / PB;
    int s = b * chunk, e = min(E, s + chunk);
    for (int i = s + t; i < e; i += 256) {
        u32 dv = (u32)dst[i], sv = (u32)src[i];
        u32 p = atomicAdd(&cd[dv >> 8], 1u);
        part[p] = ((dv & 255u) << 24) | sv;
        u32 q = atomicAdd(&cs[sv >> 8], 1u);
        part[q] = sv;
    }
}

// ---- pass 3: per-bucket exact build: rowptr, nd, csr_src, ns ----
__global__ __launch_bounds__(256) void build_kernel(
    const u32* __restrict__ part, const int* __restrict__ off,
    int* __restrict__ rowptr, float* __restrict__ nd, float* __restrict__ ns,
    int* __restrict__ csr_src, int N, int E, int NB, int M) {
    __shared__ u32 lh[256];
    __shared__ u32 cur[256];
    __shared__ int wsum[4];
    int t = threadIdx.x, k = blockIdx.x;
    int lane = t & 63, wid = t >> 6;
    int node = k * 256 + t;

    int beg = off[(size_t)k * PB];
    int end = (k + 1 < NB) ? off[(size_t)(k + 1) * PB] : E;

    lh[t] = 0;
    __syncthreads();
    for (int i = beg + t; i < end; i += 256)
        atomicAdd(&lh[part[i] >> 24], 1u);
    __syncthreads();

    int cnt = (int)lh[t];
    int sc = wave_incl_scan(cnt, lane);
    if (lane == 63) wsum[wid] = sc;
    __syncthreads();
    int add = 0;
    for (int w = 0; w < wid; ++w) add += wsum[w];
    int ex = sc - cnt + add;

    if (node < N) {
        rowptr[node] = beg + ex;
        nd[node] = rsqrtf(fmaxf((float)cnt, 1.0f));
    }
    if (k == 0 && t == 0) rowptr[N] = E;
    cur[t] = (u32)(beg + ex);
    __syncthreads();

    for (int i = beg + t; i < end; i += 256) {
        u32 v = part[i];
        u32 pos = atomicAdd(&cur[v >> 24], 1u);
        csr_src[pos] = (int)(v & 0xFFFFFFu);
    }

    // src side: exact outdeg histogram -> ns (absolute offsets into part[E:2E))
    int beg2 = off[(size_t)M + (size_t)k * PB];
    int end2 = (k + 1 < NB) ? off[(size_t)M + (size_t)(k + 1) * PB] : 2 * E;
    __syncthreads();
    lh[t] = 0;
    __syncthreads();
    for (int i = beg2 + t; i < end2; i += 256)
        atomicAdd(&lh[part[i] & 255u], 1u);
    __syncthreads();
    if (node < N) ns[node] = rsqrtf(fmaxf((float)lh[t], 1.0f));
}

// ---- gather (layer 1): 2 nodes per wave (lanes 0-31 / 32-63), uint2 (8B) per lane ----
// h2 = relu(nd * sum t1[src] + b1); t1/h2 bf16 128-wide (row = 32 uint2).
__global__ __launch_bounds__(256, 8) void gather128_kernel(
    const uint2* __restrict__ tp, const int* __restrict__ rowptr,
    const int* __restrict__ csr_src, const float* __restrict__ nd,
    const float* __restrict__ bias, uint2* __restrict__ out, int N) {
    int tid = threadIdx.x;
    int lane = tid & 63;
    int half = lane >> 5;
    int w = lane & 31;                 // word pair: cols 4w..4w+3
    int node = blockIdx.x * 8 + ((tid >> 6) << 1) + half;
    bool valid = node < N;
    int nc = valid ? node : 0;
    int beg = rowptr[nc];
    int cnt = valid ? (rowptr[nc + 1] - beg) : 0;
    const int* ip = csr_src + beg;

    float a0 = 0.f, a1 = 0.f, a2 = 0.f, a3 = 0.f;
    int j = 0;
    for (; j + 8 <= cnt; j += 8) {
        int s[8];
#pragma unroll
        for (int k = 0; k < 8; ++k) s[k] = ip[j + k];
        uint2 v[8];
#pragma unroll
        for (int k = 0; k < 8; ++k) v[k] = tp[(size_t)s[k] * 32 + w];
#pragma unroll
        for (int k = 0; k < 8; ++k) {
            a0 += bf_lo(v[k].x); a1 += bf_hi(v[k].x);
            a2 += bf_lo(v[k].y); a3 += bf_hi(v[k].y);
        }
    }
    if (j + 4 <= cnt) {
        int s[4];
#pragma unroll
        for (int k = 0; k < 4; ++k) s[k] = ip[j + k];
        uint2 v[4];
#pragma unroll
        for (int k = 0; k < 4; ++k) v[k] = tp[(size_t)s[k] * 32 + w];
#pragma unroll
        for (int k = 0; k < 4; ++k) {
            a0 += bf_lo(v[k].x); a1 += bf_hi(v[k].x);
            a2 += bf_lo(v[k].y); a3 += bf_hi(v[k].y);
        }
        j += 4;
    }
    if (j + 2 <= cnt) {
        uint2 v0 = tp[(size_t)ip[j] * 32 + w];
        uint2 v1 = tp[(size_t)ip[j + 1] * 32 + w];
        a0 += bf_lo(v0.x) + bf_lo(v1.x); a1 += bf_hi(v0.x) + bf_hi(v1.x);
        a2 += bf_lo(v0.y) + bf_lo(v1.y); a3 += bf_hi(v0.y) + bf_hi(v1.y);
        j += 2;
    }
    if (j < cnt) {
        uint2 v0 = tp[(size_t)ip[j] * 32 + w];
        a0 += bf_lo(v0.x); a1 += bf_hi(v0.x);
        a2 += bf_lo(v0.y); a3 += bf_hi(v0.y);
    }

    if (valid) {
        float sc = nd[nc];
        float4 bv = reinterpret_cast<const float4*>(bias)[w];
        float r0 = fmaxf(a0 * sc + bv.x, 0.f);
        float r1 = fmaxf(a1 * sc + bv.y, 0.f);
        float r2 = fmaxf(a2 * sc + bv.z, 0.f);
        float r3 = fmaxf(a3 * sc + bv.w, 0.f);
        uint2 o;
        o.x = f2bf(r0) | (f2bf(r1) << 16);
        o.y = f2bf(r2) | (f2bf(r3) << 16);
        out[(size_t)node * 32 + w] = o;
    }
}

// ---- gather (layer 2): 2 nodes per wave, u32 (4B) per lane; out f32 64-wide ----
__global__ __launch_bounds__(256, 8) void gather64_kernel(
    const u32* __restrict__ tp, const int* __restrict__ rowptr,
    const int* __restrict__ csr_src, const float* __restrict__ nd,
    const float* __restrict__ bias, float2* __restrict__ out, int N) {
    int tid = threadIdx.x;
    int lane = tid & 63;
    int half = lane >> 5;
    int w = lane & 31;                 // cols 2w, 2w+1
    int node = blockIdx.x * 8 + ((tid >> 6) << 1) + half;
    bool valid = node < N;
    int nc = valid ? node : 0;
    int beg = rowptr[nc];
    int cnt = valid ? (rowptr[nc + 1] - beg) : 0;
    const int* ip = csr_src + beg;

    float a0 = 0.f, a1 = 0.f;
    int j = 0;
    for (; j + 8 <= cnt; j += 8) {
        int s[8];
#pragma unroll
        for (int k = 0; k < 8; ++k) s[k] = ip[j + k];
        u32 v[8];
#pragma unroll
        for (int k = 0; k < 8; ++k) v[k] = tp[(size_t)s[k] * 32 + w];
#pragma unroll
        for (int k = 0; k < 8; ++k) { a0 += bf_lo(v[k]); a1 += bf_hi(v[k]); }
    }
    if (j + 4 <= cnt) {
        int s[4];
#pragma unroll
        for (int k = 0; k < 4; ++k) s[k] = ip[j + k];
        u32 v[4];
#pragma unroll
        for (int k = 0; k < 4; ++k) v[k] = tp[(size_t)s[k] * 32 + w];
#pragma unroll
        for (int k = 0; k < 4; ++k) { a0 += bf_lo(v[k]); a1 += bf_hi(v[k]); }
        j += 4;
    }
    if (j + 2 <= cnt) {
        u32 v0 = tp[(size_t)ip[j] * 32 + w];
        u32 v1 = tp[(size_t)ip[j + 1] * 32 + w];
        a0 += bf_lo(v0) + bf_lo(v1);
        a1 += bf_hi(v0) + bf_hi(v1);
        j += 2;
    }
    if (j < cnt) {
        u32 v0 = tp[(size_t)ip[j] * 32 + w];
        a0 += bf_lo(v0); a1 += bf_hi(v0);
    }

    if (valid) {
        float sc = nd[nc];
        float2 bv = reinterpret_cast<const float2*>(bias)[w];
        float2 o;
        o.x = a0 * sc + bv.x;
        o.y = a1 * sc + bv.y;
        out[(size_t)node * 32 + w] = o;
    }
}

// ---- MFMA GEMM: out[row][:] = bf16( (A[row] @ W) * scale[row] ), W f32 [DIN][DOUT] ----
template <int DOUT, bool ABF16>
__global__ __launch_bounds__(256) void gemm_mfma_kernel(
    const void* __restrict__ Av, const float* __restrict__ W,
    const float* __restrict__ scale, u16* __restrict__ out, int n) {
    constexpr int NT = DOUT / 16;       // col tiles
    constexpr int WK = DIN + 8;         // padded k-stride in bf16 units
    __shared__ u16 Wt[DOUT * WK];

    for (int i = threadIdx.x; i < DIN * DOUT; i += 256) {
        int k = i / DOUT, c = i % DOUT;
        Wt[c * WK + k] = (u16)f2bf(W[i]);
    }

    int lane = threadIdx.x & 63;
    int wid = threadIdx.x >> 6;
    int row = blockIdx.x * 64 + wid * 16 + (lane & 15);
    int rc = min(row, n - 1);
    int kg = lane >> 4;                 // k-group 0..3

    bf16x8 afrag[4];
    if (ABF16) {
        const u16* ap = (const u16*)Av + (size_t)rc * DIN + kg * 8;
#pragma unroll
        for (int s = 0; s < 4; ++s) {
            uint4 v = *reinterpret_cast<const uint4*>(ap + s * 32);
            afrag[s] = *reinterpret_cast<bf16x8*>(&v);
        }
    } else {
        const float* ap = (const float*)Av + (size_t)rc * DIN + kg * 8;
#pragma unroll
        for (int s = 0; s < 4; ++s) {
            float4 v0 = *reinterpret_cast<const float4*>(ap + s * 32);
            float4 v1 = *reinterpret_cast<const float4*>(ap + s * 32 + 4);
            uint4 v;
            v.x = f2bf(v0.x) | (f2bf(v0.y) << 16);
            v.y = f2bf(v0.z) | (f2bf(v0.w) << 16);
            v.z = f2bf(v1.x) | (f2bf(v1.y) << 16);
            v.w = f2bf(v1.z) | (f2bf(v1.w) << 16);
            afrag[s] = *reinterpret_cast<bf16x8*>(&v);
        }
    }

    f32x4 acc[NT];
#pragma unroll
    for (int t = 0; t < NT; ++t) acc[t] = (f32x4){0.f, 0.f, 0.f, 0.f};

    __syncthreads();                    // Wt ready

#pragma unroll
    for (int t = 0; t < NT; ++t) {
        const u16* wp = Wt + (t * 16 + (lane & 15)) * WK + kg * 8;
#pragma unroll
        for (int s = 0; s < 4; ++s) {
            uint4 wv = *reinterpret_cast<const uint4*>(wp + s * 32);
            bf16x8 wfrag = *reinterpret_cast<bf16x8*>(&wv);
            acc[t] = __builtin_amdgcn_mfma_f32_16x16x32_bf16(wfrag, afrag[s], acc[t], 0, 0, 0);
        }
    }

    if (row < n) {
        float sc = scale[row];
        u16* op = out + (size_t)row * DOUT + kg * 4;
#pragma unroll
        for (int t = 0; t < NT; ++t) {
            uint2 v;
            v.x = f2bf(acc[t][0] * sc) | (f2bf(acc[t][1] * sc) << 16);
            v.y = f2bf(acc[t][2] * sc) | (f2bf(acc[t][3] * sc) << 16);
            *reinterpret_cast<uint2*>(op + t * 16) = v;
        }
    }
}

extern "C" void kernel_launch(void* const* d_in, const int* in_sizes, int n_in,
                              void* d_out, int out_size, void* d_ws, size_t ws_size,
                              hipStream_t stream) {
    const float* feature = (const float*)d_in[0];
    const int*   src     = (const int*)d_in[1];
    const int*   dst     = (const int*)d_in[2];
    const float* W1      = (const float*)d_in[3];
    const float* b1      = (const float*)d_in[4];
    const float* W2      = (const float*)d_in[5];
    const float* b2      = (const float*)d_in[6];

    const int N = in_sizes[0] / DIN;
    const int E = in_sizes[1];
    const int NB = (N + 255) >> 8;            // buckets (<=512 for N<=131072)
    const int M = NB * PB;                    // per-side count-matrix size
    const int M2 = 2 * M;                     // concatenated (dst|src)
    const int nbm = (M2 + 255) / 256;

    char* ws = (char*)d_ws;
    size_t off_b = 0;
    auto take = [&](size_t bytes) -> void* {
        void* p = ws + off_b;
        off_b += (bytes + 255) & ~(size_t)255;
        return p;
    };
    float* ns      = (float*)take((size_t)N * 4);
    float* nd      = (float*)take((size_t)N * 4);
    int*   rowptr  = (int*)take((size_t)(N + 1) * 4);
    int*   csr_src = (int*)take((size_t)E * 4);
    u32*   mat     = (u32*)take((size_t)M2 * 4);
    int*   off     = (int*)take((size_t)M2 * 4);
    int*   bs      = (int*)take((size_t)(nbm + 4) * 4);
    u32*   part    = (u32*)take((size_t)2 * E * 4);
    u16*   t1      = (u16*)take((size_t)N * DIN * 2);  // reused as t2 (N*64 bf16)
    u16*   h2      = (u16*)take((size_t)N * DIN * 2);

    // CSR build: hist -> single concatenated scan -> partition -> per-bucket build
    hist_kernel<<<PB, 256, 0, stream>>>(src, dst, mat, E, NB, M);
    scan_block_kernel<<<nbm, 256, 0, stream>>>((const int*)mat, off, bs, M2);
    scan_sums_kernel<<<1, 256, 0, stream>>>(bs, nbm);
    add_off2_kernel<<<nbm, 256, 0, stream>>>(off, bs, M2);
    part_kernel<<<PB, 256, 0, stream>>>(src, dst, off, part, E, NB, M);
    build_kernel<<<NB, 256, 0, stream>>>(part, off, rowptr, nd, ns, csr_src, N, E, NB, M);

    // Layer 1: t1 = bf16((X @ W1) * ns); h2 = bf16(relu(gather(t1) * nd + b1))
    gemm_mfma_kernel<128, false><<<(N + 63) / 64, 256, 0, stream>>>(feature, W1, ns, t1, N);
    gather128_kernel<<<(N + 7) / 8, 256, 0, stream>>>(
        (const uint2*)t1, rowptr, csr_src, nd, b1, (uint2*)h2, N);

    // Layer 2: t2 = bf16((h2 @ W2) * ns); out = gather(t2) * nd + b2 (f32)
    gemm_mfma_kernel<64, true><<<(N + 63) / 64, 256, 0, stream>>>(h2, W2, ns, t1, N);
    gather64_kernel<<<(N + 7) / 8, 256, 0, stream>>>(
        (const u32*)t1, rowptr, csr_src, nd, b2, (float2*)d_out, N);
}